// Round 10
// baseline (264.389 us; speedup 1.0000x reference)
//
#include <hip/hip_runtime.h>
#include <cstdint>
#include <cstddef>

// Problem constants
#define R_DIM   128
#define R2_DIM  64
#define MIX     32
#define IN_DIM  512
#define HID     256
#define B_SZ    256
#define T_SZ    16
#define MAX_IT  12

// Workspace layout (float offsets)
#define OFF_G    0           // 16384 floats (row-major 128x128, pre-folded M = 0.8I - 0.2G, symmetric)
#define OFF_U    24576       // 4096*128
#define OFF_SX   548864      // 4096
#define OFF_FLAG 552960      // 1 int: 1 = absorbing fast mode (hypernet(0) == 0)
#define OFF_LOSS 552961      // 48 floats: [3][16] per-t loss partials (fast mode)
#define OFF_CNT  553012      // 1 int: fast-path completion counter

__device__ __forceinline__ float softt(float v, float lam) {
  float a = fabsf(v) - lam;
  return a > 0.f ? (v > 0.f ? a : -a) : 0.f;
}

__device__ __forceinline__ float rdlane(float v, int lane) {
  int i = __builtin_amdgcn_readlane(__float_as_int(v), lane);
  return __int_as_float(i);
}

__device__ __forceinline__ float wsum_all(float v) {  // within wave64
#pragma unroll
  for (int off = 32; off; off >>= 1) v += __shfl_xor(v, off, 64);
  return v;
}

__device__ __forceinline__ float wsum(float v) {  // lane 0 of each wave
#pragma unroll
  for (int off = 32; off; off >>= 1) v += __shfl_down(v, off, 64);
  return v;
}

// Sum of the two kh-half partials held by lanes l and l+32 (a=b form validated
// green in R3/R5/R6 benches). Pure VALU, no LDS round-trip.
__device__ __forceinline__ float pairsum32(float pm) {
  float a = pm, b = pm;
  asm volatile("v_permlane32_swap_b32 %0, %1" : "+v"(a), "+v"(b));
  return a + b;
}

// =============== COLD hypernet path: __noinline__, 64-lane (wave 0 only) ======
__device__ void ensure_c_dev(int l, const float* __restrict__ T2, float* cS,
                             int* cstL, const float* rpL) {
  if (cstL[0]) return;  // wave-0-only caller: uniform
  for (int p = l; p < MIX * R_DIM; p += 64) {
    const float* row = T2 + (size_t)p * R_DIM;
    float acc = 0.f;
    for (int j4 = 0; j4 < R_DIM / 4; j4++) {
      float4 w4 = *(const float4*)(row + j4 * 4);
      float4 r4 = *(const float4*)(rpL + j4 * 4);
      acc += w4.x * r4.x + w4.y * r4.y + w4.z * r4.z + w4.w * r4.w;
    }
    cS[(p >> 7) * 129 + (p & 127)] = acc;
  }
  if (l == 0) cstL[0] = 1;
}

__device__ __noinline__ float2 rhat_cold(int l, const float* __restrict__ T2,
                                         float* cS, int* cstL,
                                         const float* rpL, const float* wL) {
  ensure_c_dev(l, T2, cS, cstL, rpL);
  float a0 = 0.f, a1 = 0.f;
#pragma unroll
  for (int m4 = 0; m4 < 8; m4++) {
    float4 w4 = *(const float4*)&wL[m4 * 4];
    int mb = m4 * 4;
    a0 += w4.x * cS[(mb + 0) * 129 + l] + w4.y * cS[(mb + 1) * 129 + l] +
          w4.z * cS[(mb + 2) * 129 + l] + w4.w * cS[(mb + 3) * 129 + l];
    a1 += w4.x * cS[(mb + 0) * 129 + 64 + l] + w4.y * cS[(mb + 1) * 129 + 64 + l] +
          w4.z * cS[(mb + 2) * 129 + 64 + l] + w4.w * cS[(mb + 3) * 129 + 64 + l];
  }
  return make_float2(a0, a1);
}

// returns 1 if w == 0 (zw)
__device__ __noinline__ int hyp_fwd_cold(
    int l, float r2v, int zr2,
    const float* __restrict__ h1W, const float* __restrict__ h1b,
    const float* __restrict__ lns, const float* __restrict__ lnb,
    const float* __restrict__ h2W, const float* __restrict__ h2b,
    const float* __restrict__ h3W, const float* __restrict__ h3b,
    float* aL, float* xhL, float* x2L, float* wL, float* rstdL) {
  float x1[4];
#pragma unroll
  for (int q = 0; q < 4; q++) x1[q] = h1b[l + 64 * q];
  if (!zr2) {
    for (int k = 0; k < R2_DIM; k++) {
      float rk = rdlane(r2v, k);
      if (rk != 0.f) {
#pragma unroll
        for (int q = 0; q < 4; q++) x1[q] += rk * h1W[k * HID + l + 64 * q];
      }
    }
  }
  float s1 = x1[0] + x1[1] + x1[2] + x1[3];
  float s2 = x1[0] * x1[0] + x1[1] * x1[1] + x1[2] * x1[2] + x1[3] * x1[3];
  s1 = wsum_all(s1); s2 = wsum_all(s2);
  float mu = s1 * (1.f / HID);
  float var = s2 * (1.f / HID) - mu * mu;
  float rstd = rsqrtf(var + 1e-6f);
  if (l == 0) rstdL[0] = rstd;
  bool anz = false;
#pragma unroll
  for (int q = 0; q < 4; q++) {
    float xh = (x1[q] - mu) * rstd;
    xhL[l + 64 * q] = xh;
    float y = xh * lns[l + 64 * q] + lnb[l + 64 * q];
    float a = (y > 0.f) ? y : expm1f(y);
    aL[l + 64 * q] = a;
    anz |= (a != 0.f);
  }
  bool za = (__ballot(anz) == 0ull);
  float x2[4];
#pragma unroll
  for (int q = 0; q < 4; q++) x2[q] = h2b[l + 64 * q];
  if (!za) {
    for (int k4 = 0; k4 < HID / 4; k4++) {
      float4 a4 = *(const float4*)&aL[k4 * 4];
#pragma unroll
      for (int c = 0; c < 4; c++) {
        float ac = (&a4.x)[c];
        int k = k4 * 4 + c;
#pragma unroll
        for (int q = 0; q < 4; q++) x2[q] += ac * h2W[(size_t)k * HID + l + 64 * q];
      }
    }
  }
  bool x2nz = false;
#pragma unroll
  for (int q = 0; q < 4; q++) { x2L[l + 64 * q] = x2[q]; x2nz |= (x2[q] != 0.f); }
  bool zx2 = (__ballot(x2nz) == 0ull);
  int m = l & 31, kh = l >> 5;
  float p = 0.f;
  if (!zx2) {
    for (int kk = 0; kk < 128; kk++) {
      int k = kh * 128 + kk;
      p += x2L[k] * h3W[k * MIX + m];
    }
  }
  p += __shfl_xor(p, 32, 64);
  float wv = 0.f;
  if (l < 32) { wv = fmaxf(h3b[l] + p, 0.f); wL[l] = wv; }
  return (__ballot(wv != 0.f) == 0ull) ? 1 : 0;
}

// returns: .x = new r2, .y = flags bitcast (bit0 changed, bit1 zr2)
__device__ __noinline__ float2 hyp_bwd_cold(
    int l, float r2v, int zw,
    const float* __restrict__ T2,
    const float* __restrict__ h1W, const float* __restrict__ lns,
    const float* __restrict__ h2W, const float* __restrict__ h3W,
    float* cS, int* cstL, const float* rpL, const float* eL,
    const float* aL, const float* xhL, const float* wL,
    float* dx3L, float* dx2L, float* dx1L, const float* rstdL) {
  bool zd3 = true;
  if (!zw) {
    ensure_c_dev(l, T2, cS, cstL, rpL);
    int m = l & 31, ih = l >> 5;
    float p = 0.f;
    for (int ii = 0; ii < 64; ii++) {
      int i = ih * 64 + ii;
      p += eL[i] * cS[m * 129 + i];
    }
    p += __shfl_xor(p, 32, 64);
    float d3 = 0.f;
    if (l < 32) { d3 = (wL[l] > 0.f) ? (-2.f * p) : 0.f; dx3L[l] = d3; }
    zd3 = (__ballot(d3 != 0.f) == 0ull);
  }
  float g = 0.f;
  if (!zd3) {
    float rstd = rstdL[0];
    float dx2[4] = {0.f, 0.f, 0.f, 0.f};
#pragma unroll
    for (int m4 = 0; m4 < 8; m4++) {
      float4 d4 = *(const float4*)&dx3L[m4 * 4];
#pragma unroll
      for (int q = 0; q < 4; q++) {
        const float* r3 = h3W + (size_t)(l + 64 * q) * MIX + m4 * 4;
        dx2[q] += d4.x * r3[0] + d4.y * r3[1] + d4.z * r3[2] + d4.w * r3[3];
      }
    }
#pragma unroll
    for (int q = 0; q < 4; q++) dx2L[l + 64 * q] = dx2[q];
    float dxh[4];
    float s1 = 0.f, s2 = 0.f;
#pragma unroll
    for (int q = 0; q < 4; q++) {
      float da = 0.f;
      const float* row = h2W + (size_t)(l + 64 * q) * HID;
      for (int k4 = 0; k4 < HID / 4; k4++) {
        float4 w4 = *(const float4*)(row + k4 * 4);
        float4 d4 = *(const float4*)&dx2L[k4 * 4];
        da += w4.x * d4.x + w4.y * d4.y + w4.z * d4.z + w4.w * d4.w;
      }
      float a = aL[l + 64 * q];
      float dy = da * (a > 0.f ? 1.f : (a + 1.f));
      dxh[q] = dy * lns[l + 64 * q];
      s1 += dxh[q]; s2 += dxh[q] * xhL[l + 64 * q];
    }
    s1 = wsum_all(s1); s2 = wsum_all(s2);
#pragma unroll
    for (int q = 0; q < 4; q++) {
      float dx1 = rstd * (dxh[q] - s1 * (1.f / HID) - xhL[l + 64 * q] * (s2 * (1.f / HID)));
      dx1L[l + 64 * q] = dx1;
    }
    const float* row1 = h1W + (size_t)l * HID;
    for (int j4 = 0; j4 < HID / 4; j4++) {
      float4 w4 = *(const float4*)(row1 + j4 * 4);
      float4 d4 = *(const float4*)&dx1L[j4 * 4];
      g += w4.x * d4.x + w4.y * d4.y + w4.z * d4.z + w4.w * d4.w;
    }
  }
  float r2n = softt(r2v - 0.1f * g, 0.001f);
  int fl = 0;
  if (__ballot(r2n != r2v) != 0ull) fl |= 1;
  if (__ballot(r2n != 0.f) == 0ull) fl |= 2;
  return make_float2(r2n, __int_as_float(fl));
}

// ---------------- prep: G (folded), U, SX, flag, zero loss slots --------------
__global__ __launch_bounds__(256) void k_prep(const float* __restrict__ X,
                                              const float* __restrict__ decb,
                                              const float* __restrict__ decW,
                                              const float* __restrict__ h1W,
                                              const float* __restrict__ h1b,
                                              const float* __restrict__ lns,
                                              const float* __restrict__ lnb,
                                              const float* __restrict__ h2W,
                                              const float* __restrict__ h2b,
                                              const float* __restrict__ h3W,
                                              const float* __restrict__ h3b,
                                              float* __restrict__ ws,
                                              float* __restrict__ out) {
  __shared__ __align__(16) float As[8][IN_DIM];    // 16 KB
  __shared__ float scr[256];
  __shared__ __align__(16) float aF[HID], xhF[HID], x2F[HID];
  __shared__ __align__(16) float wF[MIX];
  __shared__ float rsF[1];
  float* G = ws + OFF_G;
  float* U = ws + OFF_U;
  float* SX = ws + OFF_SX;
  const int tid = threadIdx.x;
  const int bx = blockIdx.x;

  if (bx == 528) {  // absorbing-state probe, wave 0 only
    if (tid < 64) {
      int z = hyp_fwd_cold(tid, 0.f, 1, h1W, h1b, lns, lnb, h2W, h2b, h3W, h3b,
                           aF, xhF, x2F, wF, rsF);
      if (tid == 0) ((int*)(ws + OFF_FLAG))[0] = z;
    }
    return;
  }
  const bool isG = (bx >= 512);

  if (bx == 0 && tid < 3) out[tid] = 0.f;             // loss accumulators (serial)
  if (bx == 0 && tid < 48) ws[OFF_LOSS + tid] = 0.f;  // loss slots (fast)
  if (bx == 0 && tid == 48) ((int*)(ws + OFF_CNT))[0] = 0;  // completion counter

  // ---- stage A rows (X - b, or decW rows for G blocks) + SX partials ----
  {
    int g = tid >> 5;             // row 0..7
    int f0 = tid & 31;            // float4 slot base
    if (!isG) {
      int row0 = bx * 8;
      float p = 0.f;
#pragma unroll
      for (int q = 0; q < 4; q++) {
        int f4 = f0 + 32 * q;
        float4 xv = *reinterpret_cast<const float4*>(X + (size_t)(row0 + g) * IN_DIM + f4 * 4);
        float4 bv = *reinterpret_cast<const float4*>(decb + f4 * 4);
        float4 v = make_float4(xv.x - bv.x, xv.y - bv.y, xv.z - bv.z, xv.w - bv.w);
        *reinterpret_cast<float4*>(&As[g][f4 * 4]) = v;
        p += v.x * v.x + v.y * v.y + v.z * v.z + v.w * v.w;
      }
      scr[tid] = p;
    } else {
      int row0 = (bx - 512) * 8;
#pragma unroll
      for (int q = 0; q < 4; q++) {
        int f4 = f0 + 32 * q;
        float4 v = *reinterpret_cast<const float4*>(decW + (size_t)(row0 + g) * IN_DIM + f4 * 4);
        *reinterpret_cast<float4*>(&As[g][f4 * 4]) = v;
      }
    }
  }
  __syncthreads();
  if (!isG && tid < 8) {
    float s = 0.f;
#pragma unroll
    for (int q = 0; q < 32; q++) s += scr[tid * 32 + q];
    SX[bx * 8 + tid] = s;
  }

  const int j = tid & 127;        // output column
  const int gh = tid >> 7;        // row-half (4 rows each)
  float acc[4] = {0.f, 0.f, 0.f, 0.f};
  const float* wrow = decW + (size_t)j * IN_DIM;

#pragma unroll 4
  for (int k4 = 0; k4 < IN_DIM / 4; k4++) {
    float4 w4 = *reinterpret_cast<const float4*>(wrow + k4 * 4);
#pragma unroll
    for (int gi = 0; gi < 4; gi++) {
      // gg uniform per wave -> As reads are broadcasts
      float4 a4 = *reinterpret_cast<const float4*>(&As[gh * 4 + gi][k4 * 4]);
      acc[gi] += w4.x * a4.x + w4.y * a4.y + w4.z * a4.z + w4.w * a4.w;
    }
  }

  if (!isG) {
    int row0 = bx * 8;
#pragma unroll
    for (int gi = 0; gi < 4; gi++)
      U[(size_t)(row0 + gh * 4 + gi) * R_DIM + j] = acc[gi];
  } else {
    int row0 = (bx - 512) * 8;
#pragma unroll
    for (int gi = 0; gi < 4; gi++) {
      int rr = row0 + gh * 4 + gi;
      float gv = -0.2f * acc[gi];            // fold M = 0.8I - 0.2G
      if (rr == j) gv += 0.8f;
      G[(size_t)rr * R_DIM + j] = gv;
    }
  }
}

// ---------------- FAST path: one block per (b,t); absorbing state only -------
// R5 green body with the M-staging rewritten as 16 NAMED float4 variables
// loaded contiguously from row i (M symmetric -> row i == column i). No local
// array, no lambda, no runtime indexing: the allocator's array->scratch
// promotion (R5 remat @90us, R7/R9 spill @143-150us, all at VGPR=52) cannot
// trigger on named SSA float4s. No pins: if the allocator remats anyway, remat
// is coalesced dwordx4 row-loads == R5's 90us (bounded downside; pins turn
// remat into strictly-worse scratch spill, the R9 lesson).
#define REP16(X) X(0) X(1) X(2) X(3) X(4) X(5) X(6) X(7) \
                 X(8) X(9) X(10) X(11) X(12) X(13) X(14) X(15)

__global__ __launch_bounds__(256, 1) void k_ista(float* __restrict__ ws,
                                                 float* __restrict__ out) {
  if (((const int*)(ws + OFF_FLAG))[0] == 0) return;  // cold mode: serial path
  __shared__ __align__(16) float rbuf[2][R_DIM];
  __shared__ float scr[8];

  const int tid = threadIdx.x;
  const int w = tid >> 6;
  const int l6 = tid & 63;
  const int i = (w << 5) + (l6 & 31);
  const int kh = l6 >> 5;
  const int bt = blockIdx.x;
  const int b = bt >> 4;
  const int t = bt & 15;
  const float* Gg = ws + OFF_G;
  const float* Ug = ws + OFF_U;

  // M row i, this lane's K-half: 64 contiguous floats -> 16 named float4s.
  const float* grow = Gg + (size_t)i * R_DIM + (kh << 6);
#define LDG(n) float4 g##n = *reinterpret_cast<const float4*>(grow + (n) * 4);
  REP16(LDG)
#undef LDG

  const float u = Ug[(size_t)bt * R_DIM + i];
  const float u02 = 0.2f * u;

  // mv = (M v)_i, scalarized: 16 named float4 LDS reads + 64 FMA + pair-combine.
#define MV(OUT, VBASE) {                                                      \
    const float* vp = (VBASE) + (kh << 6);                                    \
    float p0 = 0.f, p1 = 0.f, p2 = 0.f, p3 = 0.f;                             \
    REP16(LDV)                                                                \
    REP16(FMA4)                                                               \
    OUT = pairsum32((p0 + p1) + (p2 + p3));                                   \
  }
#define LDV(n) float4 v##n = *reinterpret_cast<const float4*>(vp + (n) * 4);
#define FMA4(n) p0 += v##n.x * g##n.x; p1 += v##n.y * g##n.y;                 \
                p2 += v##n.z * g##n.z; p3 += v##n.w * g##n.w;

  // it = 0: r_prev = warm = 0 -> r = softt(0.2*u)
  float r = softt(u02, 0.001f);
  if (kh == 0) rbuf[1][i] = r;
  __syncthreads();
#pragma unroll 1
  for (int it = 1; it < MAX_IT; it++) {
    float mv;
    MV(mv, rbuf[it & 1])
    r = softt(mv + u02, 0.001f);
    if (kh == 0) rbuf[(it & 1) ^ 1][i] = r;   // write buffer != read buffer
    __syncthreads();
  }
  // last write (it=11) went to rbuf[0]; barrier done.
  float mvf;
  MV(mvf, rbuf[0])
  float gb = 0.8f * r - mvf;                   // = 0.2*(G r)_i
  float l1 = (kh == 0) ? (r * (5.f * gb) - 2.f * r * u) : 0.f;
  float l2 = (kh == 0) ? (r * r) : 0.f;
  l1 = wsum(l1); l2 = wsum(l2);
  if (l6 == 0) { scr[w * 2 + 0] = l1; scr[w * 2 + 1] = l2; }
  __syncthreads();
  if (tid == 0) {
    float s1 = scr[0] + scr[2] + scr[4] + scr[6];
    float s2 = scr[1] + scr[3] + scr[5] + scr[7];
    float sx = ws[OFF_SX + bt];
    float* loss = ws + OFF_LOSS;
    atomicAdd(&loss[0 * 16 + t], sx);          // spat_rhat: decode(0) vs x
    atomicAdd(&loss[1 * 16 + t], s1 + sx);     // spat_rbar
    atomicAdd(&loss[2 * 16 + t], s2);          // temp loss: ||r - 0||^2
    // fused finalization: last block reduces the 48 slots (replaces k_fin)
    __threadfence();
    int old = atomicAdd((int*)(ws + OFF_CNT), 1);
    if (old == B_SZ * T_SZ - 1) {
      float s[3] = {0.f, 0.f, 0.f};
#pragma unroll
      for (int k = 0; k < 3; k++)
        for (int tt = 0; tt < 16; tt++)
          s[k] += atomicAdd(&loss[k * 16 + tt], 0.f);  // coherent read
      const float inv = 1.f / (B_SZ * T_SZ);
      out[0] = s[0] * inv; out[1] = s[1] * inv; out[2] = s[2] * inv;
    }
  }
  if (t == T_SZ - 1 && kh == 0) out[3 + b * R_DIM + i] = r;
  if (t == 0 && w == 0) out[3 + B_SZ * R_DIM + b * R2_DIM + l6] = 0.f;
#undef LDV
#undef FMA4
#undef MV
}

// ---------------- SERIAL fallback: bit-faithful R0 body (proven green) -------
__global__ __launch_bounds__(256, 1) void k_main(
    float* __restrict__ ws, const float* __restrict__ T2,
    const float* __restrict__ h1W, const float* __restrict__ h1b,
    const float* __restrict__ lns, const float* __restrict__ lnb,
    const float* __restrict__ h2W, const float* __restrict__ h2b,
    const float* __restrict__ h3W, const float* __restrict__ h3b,
    float* __restrict__ out) {
  if (((const int*)(ws + OFF_FLAG))[0] != 0) return;  // fast path covers
  __shared__ __align__(16) float rbuf[2][R_DIM];
  __shared__ __align__(16) float rhL[R_DIM];
  __shared__ __align__(16) float cS[MIX * 129];
  __shared__ __align__(16) float aL[HID];
  __shared__ __align__(16) float xhL[HID];
  __shared__ __align__(16) float x2L[HID];
  __shared__ __align__(16) float dx1L[HID];
  __shared__ __align__(16) float dx2L[HID];
  __shared__ __align__(16) float wL[MIX];
  __shared__ __align__(16) float dx3L[MIX];
  __shared__ __align__(16) float eL[R_DIM];
  __shared__ __align__(16) float rpL[R_DIM];
  __shared__ float rstdL[1];
  __shared__ int cstL[1];
  __shared__ int flagL[1];

  const int tid = threadIdx.x;
  const int w = tid >> 6;
  const int l6 = tid & 63;
  const int i = (w << 5) + (l6 & 31);
  const int kh = l6 >> 5;
  const int b = blockIdx.x;
  const float* Gg = ws + OFF_G;
  const float* Ug = ws + OFF_U;
  const float* SXg = ws + OFF_SX;

  float r2v = 0.f;
  bool zr2 = true, rhv;

  if (w == 0) {
    int z = hyp_fwd_cold(l6, 0.f, 1, h1W, h1b, lns, lnb, h2W, h2b, h3W, h3b,
                         aL, xhL, x2L, wL, rstdL);
    if (l6 == 0) flagL[0] = z;
  }
  __syncthreads();
  bool zw = flagL[0] != 0;

  float Ga[64];
#pragma unroll
  for (int kk = 0; kk < 64; kk++)
    Ga[kk] = Gg[(size_t)(kh * 64 + kk) * R_DIM + i];

  float rOwn = 0.f;
  float lc0 = 0.f, lc1 = 0.f, lc2 = 0.f, sxa = 0.f;

  auto mvhalf = [&](const float* vptr) {
    const float* vp = vptr + (kh << 6);
    float p0 = 0.f, p1 = 0.f, p2 = 0.f, p3 = 0.f;
#pragma unroll
    for (int k4 = 0; k4 < 16; k4++) {
      float4 v4 = *reinterpret_cast<const float4*>(vp + k4 * 4);
      p0 += v4.x * Ga[k4 * 4 + 0];
      p1 += v4.y * Ga[k4 * 4 + 1];
      p2 += v4.z * Ga[k4 * 4 + 2];
      p3 += v4.w * Ga[k4 * 4 + 3];
    }
    float pm = (p0 + p1) + (p2 + p3);
    return pm + __shfl_xor(pm, 32, 64);
  };

  float rh_own = 0.f;
  auto refresh_rh = [&]() {
    if (zw) { rh_own = 0.f; return; }
    __syncthreads();
    if (w == 0) {
      float2 rr = rhat_cold(l6, T2, cS, cstL, rpL, wL);
      rhL[l6] = rr.x; rhL[64 + l6] = rr.y;
    }
    __syncthreads();
    rh_own = rhL[i];
  };

  float un = Ug[(size_t)(b * T_SZ) * R_DIM + i];
  float sxn = SXg[b * T_SZ];

#pragma unroll 1
  for (int t = 0; t < T_SZ; t++) {
    float u = un, sxv = sxn;
    if (t < T_SZ - 1) {
      un = Ug[(size_t)(b * T_SZ + t + 1) * R_DIM + i];
      sxn = SXg[b * T_SZ + t + 1];
    }
    float u02 = 0.2f * u;
    if (kh == 0) rpL[i] = rOwn;
    if (tid == 0) cstL[0] = 0;
    refresh_rh();
    rhv = true;
    rOwn = rh_own;
    __syncthreads();
    if (kh == 0) rbuf[0][i] = rOwn;
    __syncthreads();
    bool rzero = zw;
#pragma unroll 1
    for (int it = 0; it < MAX_IT; it++) {
      if (!rhv) { refresh_rh(); rhv = true; }
      float mv = 0.f;
      if (!rzero) mv = mvhalf(rbuf[it & 1]);
      rzero = false;
      float rNew = softt(mv + 0.2f * rh_own + u02, 0.001f);
      if (kh == 0) {
        eL[i] = rOwn - rh_own;
        rbuf[(it & 1) ^ 1][i] = rNew;
      }
      rOwn = rNew;
      __syncthreads();
      if (!(zw && zr2)) {
        if (w == 0) {
          float2 br = hyp_bwd_cold(l6, r2v, zw ? 1 : 0, T2, h1W, lns, h2W, h3W,
                                   cS, cstL, rpL, eL, aL, xhL, wL,
                                   dx3L, dx2L, dx1L, rstdL);
          r2v = br.x;
          if (l6 == 0) flagL[0] = __float_as_int(br.y);
        }
        __syncthreads();
        int fl = flagL[0];
        zr2 = (fl & 2) != 0;
        if (fl & 1) {
          if (w == 0) {
            int z = hyp_fwd_cold(l6, r2v, zr2 ? 1 : 0, h1W, h1b, lns, lnb,
                                 h2W, h2b, h3W, h3b, aL, xhL, x2L, wL, rstdL);
            if (l6 == 0) flagL[0] = z;
          }
          __syncthreads();
          zw = flagL[0] != 0;
          rhv = false;
        }
      }
    }
    if (!rhv) { refresh_rh(); rhv = true; }
    {
      float mv = mvhalf(rbuf[MAX_IT & 1]);
      float gb = 0.8f * rOwn - mv;
      if (kh == 0) lc1 += rOwn * (5.f * gb) - 2.f * rOwn * u;
      if (zw) {
        if (kh == 0) lc2 += rOwn * rOwn;
      } else {
        float mvh = mvhalf(rhL);
        float gh = 0.8f * rh_own - mvh;
        if (kh == 0) {
          lc0 += rh_own * (5.f * gh) - 2.f * rh_own * u;
          float d = rOwn - rh_own;
          lc2 += d * d;
        }
      }
      if (tid == 0) sxa += sxv;
    }
  }

  const float inv = 1.f / (B_SZ * T_SZ);
  float t0 = wsum(lc0), t1 = wsum(lc1), t2 = wsum(lc2);
  if (l6 == 0) {
    float s = (w == 0) ? sxa : 0.f;
    atomicAdd(&out[0], (t0 + s) * inv);
    atomicAdd(&out[1], (t1 + s) * inv);
    atomicAdd(&out[2], t2 * inv);
  }
  if (kh == 0) out[3 + b * R_DIM + i] = rOwn;
  if (w == 0) out[3 + B_SZ * R_DIM + b * R2_DIM + l6] = r2v;
}

extern "C" void kernel_launch(void* const* d_in, const int* in_sizes, int n_in,
                              void* d_out, int out_size, void* d_ws, size_t ws_size,
                              hipStream_t stream) {
  const float* X = (const float*)d_in[0];
  const float* decW = (const float*)d_in[1];
  const float* decb = (const float*)d_in[2];
  const float* temporal = (const float*)d_in[3];
  const float* h1W = (const float*)d_in[4];
  const float* h1b = (const float*)d_in[5];
  const float* lns = (const float*)d_in[6];
  const float* lnb = (const float*)d_in[7];
  const float* h2W = (const float*)d_in[8];
  const float* h2b = (const float*)d_in[9];
  const float* h3W = (const float*)d_in[10];
  const float* h3b = (const float*)d_in[11];
  float* ws = (float*)d_ws;  // ~2.22 MiB used
  float* out = (float*)d_out;

  k_prep<<<529, 256, 0, stream>>>(X, decb, decW, h1W, h1b, lns, lnb,
                                  h2W, h2b, h3W, h3b, ws, out);
  k_main<<<B_SZ, 256, 0, stream>>>(ws, temporal, h1W, h1b, lns, lnb,
                                   h2W, h2b, h3W, h3b, out);
  k_ista<<<B_SZ * T_SZ, 256, 0, stream>>>(ws, out);
}

// Round 11
// 261.657 us; speedup vs baseline: 1.0104x; 1.0104x over previous
//
#include <hip/hip_runtime.h>
#include <cstdint>
#include <cstddef>

// Problem constants
#define R_DIM   128
#define R2_DIM  64
#define MIX     32
#define IN_DIM  512
#define HID     256
#define B_SZ    256
#define T_SZ    16
#define MAX_IT  12

// Workspace layout (float offsets)
#define OFF_G    0           // 16384 floats (row-major 128x128, M = 0.8I - 0.2G, symmetric)
#define OFF_U    24576       // 4096*128
#define OFF_SX   548864      // 4096
#define OFF_FLAG 552960      // 1 int: 1 = absorbing fast mode (hypernet(0) == 0)
#define OFF_LOSS 552961      // 48 floats: [3][16] per-t loss partials (fast mode)
#define OFF_CNT  553012      // 1 int: fast-path completion counter
#define OFF_G2   557056      // 16384 floats: k-major tiled M copy for k_ista
                             // layout: [(kh*16 + k4)*128 + c]*4 + e ; k = kh*64+k4*4+e

__device__ __forceinline__ float softt(float v, float lam) {
  float a = fabsf(v) - lam;
  return a > 0.f ? (v > 0.f ? a : -a) : 0.f;
}

__device__ __forceinline__ float rdlane(float v, int lane) {
  int i = __builtin_amdgcn_readlane(__float_as_int(v), lane);
  return __int_as_float(i);
}

__device__ __forceinline__ float wsum_all(float v) {  // within wave64
#pragma unroll
  for (int off = 32; off; off >>= 1) v += __shfl_xor(v, off, 64);
  return v;
}

__device__ __forceinline__ float wsum(float v) {  // lane 0 of each wave
#pragma unroll
  for (int off = 32; off; off >>= 1) v += __shfl_down(v, off, 64);
  return v;
}

// Sum of the two kh-half partials held by lanes l and l+32 (a=b form validated
// green in R3/R5/R6 benches). Pure VALU, no LDS round-trip.
__device__ __forceinline__ float pairsum32(float pm) {
  float a = pm, b = pm;
  asm volatile("v_permlane32_swap_b32 %0, %1" : "+v"(a), "+v"(b));
  return a + b;
}

// =============== COLD hypernet path: __noinline__, 64-lane (wave 0 only) ======
__device__ void ensure_c_dev(int l, const float* __restrict__ T2, float* cS,
                             int* cstL, const float* rpL) {
  if (cstL[0]) return;  // wave-0-only caller: uniform
  for (int p = l; p < MIX * R_DIM; p += 64) {
    const float* row = T2 + (size_t)p * R_DIM;
    float acc = 0.f;
    for (int j4 = 0; j4 < R_DIM / 4; j4++) {
      float4 w4 = *(const float4*)(row + j4 * 4);
      float4 r4 = *(const float4*)(rpL + j4 * 4);
      acc += w4.x * r4.x + w4.y * r4.y + w4.z * r4.z + w4.w * r4.w;
    }
    cS[(p >> 7) * 129 + (p & 127)] = acc;
  }
  if (l == 0) cstL[0] = 1;
}

__device__ __noinline__ float2 rhat_cold(int l, const float* __restrict__ T2,
                                         float* cS, int* cstL,
                                         const float* rpL, const float* wL) {
  ensure_c_dev(l, T2, cS, cstL, rpL);
  float a0 = 0.f, a1 = 0.f;
#pragma unroll
  for (int m4 = 0; m4 < 8; m4++) {
    float4 w4 = *(const float4*)&wL[m4 * 4];
    int mb = m4 * 4;
    a0 += w4.x * cS[(mb + 0) * 129 + l] + w4.y * cS[(mb + 1) * 129 + l] +
          w4.z * cS[(mb + 2) * 129 + l] + w4.w * cS[(mb + 3) * 129 + l];
    a1 += w4.x * cS[(mb + 0) * 129 + 64 + l] + w4.y * cS[(mb + 1) * 129 + 64 + l] +
          w4.z * cS[(mb + 2) * 129 + 64 + l] + w4.w * cS[(mb + 3) * 129 + 64 + l];
  }
  return make_float2(a0, a1);
}

// returns 1 if w == 0 (zw)
__device__ __noinline__ int hyp_fwd_cold(
    int l, float r2v, int zr2,
    const float* __restrict__ h1W, const float* __restrict__ h1b,
    const float* __restrict__ lns, const float* __restrict__ lnb,
    const float* __restrict__ h2W, const float* __restrict__ h2b,
    const float* __restrict__ h3W, const float* __restrict__ h3b,
    float* aL, float* xhL, float* x2L, float* wL, float* rstdL) {
  float x1[4];
#pragma unroll
  for (int q = 0; q < 4; q++) x1[q] = h1b[l + 64 * q];
  if (!zr2) {
    for (int k = 0; k < R2_DIM; k++) {
      float rk = rdlane(r2v, k);
      if (rk != 0.f) {
#pragma unroll
        for (int q = 0; q < 4; q++) x1[q] += rk * h1W[k * HID + l + 64 * q];
      }
    }
  }
  float s1 = x1[0] + x1[1] + x1[2] + x1[3];
  float s2 = x1[0] * x1[0] + x1[1] * x1[1] + x1[2] * x1[2] + x1[3] * x1[3];
  s1 = wsum_all(s1); s2 = wsum_all(s2);
  float mu = s1 * (1.f / HID);
  float var = s2 * (1.f / HID) - mu * mu;
  float rstd = rsqrtf(var + 1e-6f);
  if (l == 0) rstdL[0] = rstd;
  bool anz = false;
#pragma unroll
  for (int q = 0; q < 4; q++) {
    float xh = (x1[q] - mu) * rstd;
    xhL[l + 64 * q] = xh;
    float y = xh * lns[l + 64 * q] + lnb[l + 64 * q];
    float a = (y > 0.f) ? y : expm1f(y);
    aL[l + 64 * q] = a;
    anz |= (a != 0.f);
  }
  bool za = (__ballot(anz) == 0ull);
  float x2[4];
#pragma unroll
  for (int q = 0; q < 4; q++) x2[q] = h2b[l + 64 * q];
  if (!za) {
    for (int k4 = 0; k4 < HID / 4; k4++) {
      float4 a4 = *(const float4*)&aL[k4 * 4];
#pragma unroll
      for (int c = 0; c < 4; c++) {
        float ac = (&a4.x)[c];
        int k = k4 * 4 + c;
#pragma unroll
        for (int q = 0; q < 4; q++) x2[q] += ac * h2W[(size_t)k * HID + l + 64 * q];
      }
    }
  }
  bool x2nz = false;
#pragma unroll
  for (int q = 0; q < 4; q++) { x2L[l + 64 * q] = x2[q]; x2nz |= (x2[q] != 0.f); }
  bool zx2 = (__ballot(x2nz) == 0ull);
  int m = l & 31, kh = l >> 5;
  float p = 0.f;
  if (!zx2) {
    for (int kk = 0; kk < 128; kk++) {
      int k = kh * 128 + kk;
      p += x2L[k] * h3W[k * MIX + m];
    }
  }
  p += __shfl_xor(p, 32, 64);
  float wv = 0.f;
  if (l < 32) { wv = fmaxf(h3b[l] + p, 0.f); wL[l] = wv; }
  return (__ballot(wv != 0.f) == 0ull) ? 1 : 0;
}

// returns: .x = new r2, .y = flags bitcast (bit0 changed, bit1 zr2)
__device__ __noinline__ float2 hyp_bwd_cold(
    int l, float r2v, int zw,
    const float* __restrict__ T2,
    const float* __restrict__ h1W, const float* __restrict__ lns,
    const float* __restrict__ h2W, const float* __restrict__ h3W,
    float* cS, int* cstL, const float* rpL, const float* eL,
    const float* aL, const float* xhL, const float* wL,
    float* dx3L, float* dx2L, float* dx1L, const float* rstdL) {
  bool zd3 = true;
  if (!zw) {
    ensure_c_dev(l, T2, cS, cstL, rpL);
    int m = l & 31, ih = l >> 5;
    float p = 0.f;
    for (int ii = 0; ii < 64; ii++) {
      int i = ih * 64 + ii;
      p += eL[i] * cS[m * 129 + i];
    }
    p += __shfl_xor(p, 32, 64);
    float d3 = 0.f;
    if (l < 32) { d3 = (wL[l] > 0.f) ? (-2.f * p) : 0.f; dx3L[l] = d3; }
    zd3 = (__ballot(d3 != 0.f) == 0ull);
  }
  float g = 0.f;
  if (!zd3) {
    float rstd = rstdL[0];
    float dx2[4] = {0.f, 0.f, 0.f, 0.f};
#pragma unroll
    for (int m4 = 0; m4 < 8; m4++) {
      float4 d4 = *(const float4*)&dx3L[m4 * 4];
#pragma unroll
      for (int q = 0; q < 4; q++) {
        const float* r3 = h3W + (size_t)(l + 64 * q) * MIX + m4 * 4;
        dx2[q] += d4.x * r3[0] + d4.y * r3[1] + d4.z * r3[2] + d4.w * r3[3];
      }
    }
#pragma unroll
    for (int q = 0; q < 4; q++) dx2L[l + 64 * q] = dx2[q];
    float dxh[4];
    float s1 = 0.f, s2 = 0.f;
#pragma unroll
    for (int q = 0; q < 4; q++) {
      float da = 0.f;
      const float* row = h2W + (size_t)(l + 64 * q) * HID;
      for (int k4 = 0; k4 < HID / 4; k4++) {
        float4 w4 = *(const float4*)(row + k4 * 4);
        float4 d4 = *(const float4*)&dx2L[k4 * 4];
        da += w4.x * d4.x + w4.y * d4.y + w4.z * d4.z + w4.w * d4.w;
      }
      float a = aL[l + 64 * q];
      float dy = da * (a > 0.f ? 1.f : (a + 1.f));
      dxh[q] = dy * lns[l + 64 * q];
      s1 += dxh[q]; s2 += dxh[q] * xhL[l + 64 * q];
    }
    s1 = wsum_all(s1); s2 = wsum_all(s2);
#pragma unroll
    for (int q = 0; q < 4; q++) {
      float dx1 = rstd * (dxh[q] - s1 * (1.f / HID) - xhL[l + 64 * q] * (s2 * (1.f / HID)));
      dx1L[l + 64 * q] = dx1;
    }
    const float* row1 = h1W + (size_t)l * HID;
    for (int j4 = 0; j4 < HID / 4; j4++) {
      float4 w4 = *(const float4*)(row1 + j4 * 4);
      float4 d4 = *(const float4*)&dx1L[j4 * 4];
      g += w4.x * d4.x + w4.y * d4.y + w4.z * d4.z + w4.w * d4.w;
    }
  }
  float r2n = softt(r2v - 0.1f * g, 0.001f);
  int fl = 0;
  if (__ballot(r2n != r2v) != 0ull) fl |= 1;
  if (__ballot(r2n != 0.f) == 0ull) fl |= 2;
  return make_float2(r2n, __int_as_float(fl));
}

// ---------------- prep: G (folded) + G2 (k-major tiled), U, SX, flag ----------
__global__ __launch_bounds__(256) void k_prep(const float* __restrict__ X,
                                              const float* __restrict__ decb,
                                              const float* __restrict__ decW,
                                              const float* __restrict__ h1W,
                                              const float* __restrict__ h1b,
                                              const float* __restrict__ lns,
                                              const float* __restrict__ lnb,
                                              const float* __restrict__ h2W,
                                              const float* __restrict__ h2b,
                                              const float* __restrict__ h3W,
                                              const float* __restrict__ h3b,
                                              float* __restrict__ ws,
                                              float* __restrict__ out) {
  __shared__ __align__(16) float As[8][IN_DIM];    // 16 KB
  __shared__ float scr[256];
  __shared__ __align__(16) float aF[HID], xhF[HID], x2F[HID];
  __shared__ __align__(16) float wF[MIX];
  __shared__ float rsF[1];
  float* G = ws + OFF_G;
  float* G2 = ws + OFF_G2;
  float* U = ws + OFF_U;
  float* SX = ws + OFF_SX;
  const int tid = threadIdx.x;
  const int bx = blockIdx.x;

  if (bx == 528) {  // absorbing-state probe, wave 0 only
    if (tid < 64) {
      int z = hyp_fwd_cold(tid, 0.f, 1, h1W, h1b, lns, lnb, h2W, h2b, h3W, h3b,
                           aF, xhF, x2F, wF, rsF);
      if (tid == 0) ((int*)(ws + OFF_FLAG))[0] = z;
    }
    return;
  }
  const bool isG = (bx >= 512);

  if (bx == 0 && tid < 3) out[tid] = 0.f;             // loss accumulators (serial)
  if (bx == 0 && tid < 48) ws[OFF_LOSS + tid] = 0.f;  // loss slots (fast)
  if (bx == 0 && tid == 48) ((int*)(ws + OFF_CNT))[0] = 0;  // completion counter

  // ---- stage A rows (X - b, or decW rows for G blocks) + SX partials ----
  {
    int g = tid >> 5;             // row 0..7
    int f0 = tid & 31;            // float4 slot base
    if (!isG) {
      int row0 = bx * 8;
      float p = 0.f;
#pragma unroll
      for (int q = 0; q < 4; q++) {
        int f4 = f0 + 32 * q;
        float4 xv = *reinterpret_cast<const float4*>(X + (size_t)(row0 + g) * IN_DIM + f4 * 4);
        float4 bv = *reinterpret_cast<const float4*>(decb + f4 * 4);
        float4 v = make_float4(xv.x - bv.x, xv.y - bv.y, xv.z - bv.z, xv.w - bv.w);
        *reinterpret_cast<float4*>(&As[g][f4 * 4]) = v;
        p += v.x * v.x + v.y * v.y + v.z * v.z + v.w * v.w;
      }
      scr[tid] = p;
    } else {
      int row0 = (bx - 512) * 8;
#pragma unroll
      for (int q = 0; q < 4; q++) {
        int f4 = f0 + 32 * q;
        float4 v = *reinterpret_cast<const float4*>(decW + (size_t)(row0 + g) * IN_DIM + f4 * 4);
        *reinterpret_cast<float4*>(&As[g][f4 * 4]) = v;
      }
    }
  }
  __syncthreads();
  if (!isG && tid < 8) {
    float s = 0.f;
#pragma unroll
    for (int q = 0; q < 32; q++) s += scr[tid * 32 + q];
    SX[bx * 8 + tid] = s;
  }

  const int j = tid & 127;        // output column
  const int gh = tid >> 7;        // row-half (4 rows each)
  float acc[4] = {0.f, 0.f, 0.f, 0.f};
  const float* wrow = decW + (size_t)j * IN_DIM;

#pragma unroll 4
  for (int k4 = 0; k4 < IN_DIM / 4; k4++) {
    float4 w4 = *reinterpret_cast<const float4*>(wrow + k4 * 4);
#pragma unroll
    for (int gi = 0; gi < 4; gi++) {
      // gg uniform per wave -> As reads are broadcasts
      float4 a4 = *reinterpret_cast<const float4*>(&As[gh * 4 + gi][k4 * 4]);
      acc[gi] += w4.x * a4.x + w4.y * a4.y + w4.z * a4.z + w4.w * a4.w;
    }
  }

  if (!isG) {
    int row0 = bx * 8;
#pragma unroll
    for (int gi = 0; gi < 4; gi++)
      U[(size_t)(row0 + gh * 4 + gi) * R_DIM + j] = acc[gi];
  } else {
    int row0 = (bx - 512) * 8;
#pragma unroll
    for (int gi = 0; gi < 4; gi++) {
      int rr = row0 + gh * 4 + gi;
      float gv = -0.2f * acc[gi];            // fold M = 0.8I - 0.2G
      if (rr == j) gv += 0.8f;
      G[(size_t)rr * R_DIM + j] = gv;
      // G2: k-major tiled copy for k_ista ([(kh*16+k4)*128 + c]*4 + e)
      int idx2 = (((rr >> 6) * 16 + ((rr & 63) >> 2)) * 128 + j) * 4 + (rr & 3);
      G2[idx2] = gv;
    }
  }
}

// ---------------- FAST path: 4 (b,t) per block, 2 cols x 2 bts per lane -------
// Allocator invariant (R5/R7/R8/R9/R10): ~52 VGPR target; anything live across
// barriers beyond that spills or remats. So: design FOR streaming. G is
// re-read from L2 every iteration EXPLICITLY (k-major G2 copy, coalesced
// b128), and each loaded value feeds 2 bts x (via symmetry pairing) 2 columns:
// G L2 traffic = 1024 x 12 x 128KB = 1.6GB (~45us at the measured ~35TB/s L2
// ceiling) vs R5's 3.4GB (its 90us limiter). r LDS reads are shared across the
// 2 columns: 32 b128/lane/iter for 4 output-chains. The per-iteration
// asm("":"+v"(gp)) breaks loop-invariance so no 128-float live set can form.
__global__ void k_ista(float* __restrict__ ws, float* __restrict__ out) {
  if (((const int*)(ws + OFF_FLAG))[0] == 0) return;  // cold mode: serial path
  __shared__ __align__(16) float rbuf[4][2][R_DIM];   // [local bt][dbuf][col]
  __shared__ float scr[4][4];

  const int tid = threadIdx.x;
  const int W = tid >> 6;               // wave 0..3
  const int btp = W >> 1;               // bt-group 0/1 (2 bts each)
  const int w2 = W & 1;                 // wave within group
  const int l6 = tid & 63;
  const int p = (w2 << 5) + (l6 & 31);  // 0..63; lane's column pair (p, p+64)
  const int kh = l6 >> 5;               // K-half 0/1
  const int iown = p + (kh << 6);       // column this lane WRITES
  const int bt0 = blockIdx.x * 4;
  const int la = btp * 2, lb = la + 1;  // local bt indices
  const int btA = bt0 + la, btB = bt0 + lb;
  const float* G2 = ws + OFF_G2;
  const float* Ug = ws + OFF_U;

  // G2 base for this lane: (kh,k4=0,c=p); col p+64 at +256 floats; k4 stride 512.
  const float* g2base = G2 + (size_t)kh * 8192 + (size_t)p * 4;

  const float uA = Ug[(size_t)btA * R_DIM + iown];
  const float uB = Ug[(size_t)btB * R_DIM + iown];
  const float u02A = 0.2f * uA, u02B = 0.2f * uB;

  // it = 0: r_prev = 0 -> r = softt(0.2*u)
  float rA = softt(u02A, 0.001f);
  float rB = softt(u02B, 0.001f);
  rbuf[la][1][iown] = rA;
  rbuf[lb][1][iown] = rB;
  __syncthreads();

  // body: partials for (colP,btA),(colQ,btA),(colP,btB),(colQ,btB) over kh-half
#define MV4(OUTA, OUTB, BUF) {                                                \
    const float* gp = g2base;                                                 \
    asm volatile("" : "+v"(gp));  /* break loop-invariance: no LICM set */    \
    const float* va = &rbuf[la][BUF][kh << 6];                                \
    const float* vb = &rbuf[lb][BUF][kh << 6];                                \
    float a0 = 0.f, a1 = 0.f, b0 = 0.f, b1 = 0.f;                             \
    _Pragma("unroll")                                                         \
    for (int k4 = 0; k4 < 16; k4++) {                                         \
      float4 g0 = *reinterpret_cast<const float4*>(gp + k4 * 512);            \
      float4 g1 = *reinterpret_cast<const float4*>(gp + k4 * 512 + 256);      \
      float4 x  = *reinterpret_cast<const float4*>(va + k4 * 4);              \
      float4 y  = *reinterpret_cast<const float4*>(vb + k4 * 4);              \
      a0 += x.x * g0.x + x.y * g0.y + x.z * g0.z + x.w * g0.w;                \
      a1 += x.x * g1.x + x.y * g1.y + x.z * g1.z + x.w * g1.w;                \
      b0 += y.x * g0.x + y.y * g0.y + y.z * g0.z + y.w * g0.w;                \
      b1 += y.x * g1.x + y.y * g1.y + y.z * g1.z + y.w * g1.w;                \
    }                                                                         \
    float sA0 = pairsum32(a0), sA1 = pairsum32(a1);                           \
    float sB0 = pairsum32(b0), sB1 = pairsum32(b1);                           \
    OUTA = kh ? sA1 : sA0;  /* lane's written-col matvec, bt A */             \
    OUTB = kh ? sB1 : sB0;                                                    \
  }

#pragma unroll 1
  for (int it = 1; it < MAX_IT; it++) {
    float mvA, mvB;
    MV4(mvA, mvB, it & 1)
    rA = softt(mvA + u02A, 0.001f);
    rB = softt(mvB + u02B, 0.001f);
    rbuf[la][(it & 1) ^ 1][iown] = rA;   // write buffer != read buffer
    rbuf[lb][(it & 1) ^ 1][iown] = rB;
    __syncthreads();
  }
  // last write (it=11) went to rbuf[*][0]; barrier done.
  float mvfA, mvfB;
  MV4(mvfA, mvfB, 0)
#undef MV4
  float gbA = 0.8f * rA - mvfA;          // = 0.2*(G r)_iown, bt A
  float gbB = 0.8f * rB - mvfB;
  float l1A = rA * (5.f * gbA) - 2.f * rA * uA;
  float l2A = rA * rA;
  float l1B = rB * (5.f * gbB) - 2.f * rB * uB;
  float l2B = rB * rB;
  l1A = wsum(l1A); l2A = wsum(l2A); l1B = wsum(l1B); l2B = wsum(l2B);
  if (l6 == 0) { scr[W][0] = l1A; scr[W][1] = l2A; scr[W][2] = l1B; scr[W][3] = l2B; }
  __syncthreads();
  if (tid == 0) {
    float* loss = ws + OFF_LOSS;
#pragma unroll
    for (int j = 0; j < 4; j++) {
      int gW = (j >> 1) * 2;             // first wave of the bt's group
      int c = (j & 1) * 2;               // scr column base (a/b member)
      float l1 = scr[gW][c + 0] + scr[gW + 1][c + 0];
      float l2 = scr[gW][c + 1] + scr[gW + 1][c + 1];
      int btg = bt0 + j;
      int t = btg & 15;
      float sx = ws[OFF_SX + btg];
      atomicAdd(&loss[0 * 16 + t], sx);        // spat_rhat: decode(0) vs x
      atomicAdd(&loss[1 * 16 + t], l1 + sx);   // spat_rbar
      atomicAdd(&loss[2 * 16 + t], l2);        // temp loss: ||r||^2
    }
    // fused finalization: last block reduces the 48 slots
    __threadfence();
    int old = atomicAdd((int*)(ws + OFF_CNT), 1);
    if (old == (B_SZ * T_SZ / 4) - 1) {
      float s[3] = {0.f, 0.f, 0.f};
#pragma unroll
      for (int k = 0; k < 3; k++)
        for (int tt = 0; tt < 16; tt++)
          s[k] += atomicAdd(&loss[k * 16 + tt], 0.f);  // coherent read
      const float inv = 1.f / (B_SZ * T_SZ);
      out[0] = s[0] * inv; out[1] = s[1] * inv; out[2] = s[2] * inv;
    }
  }
  if ((btA & 15) == T_SZ - 1) out[3 + (btA >> 4) * R_DIM + iown] = rA;
  if ((btB & 15) == T_SZ - 1) out[3 + (btB >> 4) * R_DIM + iown] = rB;
  if ((btA & 15) == 0 && w2 == 0)
    out[3 + B_SZ * R_DIM + (btA >> 4) * R2_DIM + l6] = 0.f;
}

// ---------------- SERIAL fallback: bit-faithful R0 body (proven green) -------
__global__ __launch_bounds__(256, 1) void k_main(
    float* __restrict__ ws, const float* __restrict__ T2,
    const float* __restrict__ h1W, const float* __restrict__ h1b,
    const float* __restrict__ lns, const float* __restrict__ lnb,
    const float* __restrict__ h2W, const float* __restrict__ h2b,
    const float* __restrict__ h3W, const float* __restrict__ h3b,
    float* __restrict__ out) {
  if (((const int*)(ws + OFF_FLAG))[0] != 0) return;  // fast path covers
  __shared__ __align__(16) float rbuf[2][R_DIM];
  __shared__ __align__(16) float rhL[R_DIM];
  __shared__ __align__(16) float cS[MIX * 129];
  __shared__ __align__(16) float aL[HID];
  __shared__ __align__(16) float xhL[HID];
  __shared__ __align__(16) float x2L[HID];
  __shared__ __align__(16) float dx1L[HID];
  __shared__ __align__(16) float dx2L[HID];
  __shared__ __align__(16) float wL[MIX];
  __shared__ __align__(16) float dx3L[MIX];
  __shared__ __align__(16) float eL[R_DIM];
  __shared__ __align__(16) float rpL[R_DIM];
  __shared__ float rstdL[1];
  __shared__ int cstL[1];
  __shared__ int flagL[1];

  const int tid = threadIdx.x;
  const int w = tid >> 6;
  const int l6 = tid & 63;
  const int i = (w << 5) + (l6 & 31);
  const int kh = l6 >> 5;
  const int b = blockIdx.x;
  const float* Gg = ws + OFF_G;
  const float* Ug = ws + OFF_U;
  const float* SXg = ws + OFF_SX;

  float r2v = 0.f;
  bool zr2 = true, rhv;

  if (w == 0) {
    int z = hyp_fwd_cold(l6, 0.f, 1, h1W, h1b, lns, lnb, h2W, h2b, h3W, h3b,
                         aL, xhL, x2L, wL, rstdL);
    if (l6 == 0) flagL[0] = z;
  }
  __syncthreads();
  bool zw = flagL[0] != 0;

  float Ga[64];
#pragma unroll
  for (int kk = 0; kk < 64; kk++)
    Ga[kk] = Gg[(size_t)(kh * 64 + kk) * R_DIM + i];

  float rOwn = 0.f;
  float lc0 = 0.f, lc1 = 0.f, lc2 = 0.f, sxa = 0.f;

  auto mvhalf = [&](const float* vptr) {
    const float* vp = vptr + (kh << 6);
    float p0 = 0.f, p1 = 0.f, p2 = 0.f, p3 = 0.f;
#pragma unroll
    for (int k4 = 0; k4 < 16; k4++) {
      float4 v4 = *reinterpret_cast<const float4*>(vp + k4 * 4);
      p0 += v4.x * Ga[k4 * 4 + 0];
      p1 += v4.y * Ga[k4 * 4 + 1];
      p2 += v4.z * Ga[k4 * 4 + 2];
      p3 += v4.w * Ga[k4 * 4 + 3];
    }
    float pm = (p0 + p1) + (p2 + p3);
    return pm + __shfl_xor(pm, 32, 64);
  };

  float rh_own = 0.f;
  auto refresh_rh = [&]() {
    if (zw) { rh_own = 0.f; return; }
    __syncthreads();
    if (w == 0) {
      float2 rr = rhat_cold(l6, T2, cS, cstL, rpL, wL);
      rhL[l6] = rr.x; rhL[64 + l6] = rr.y;
    }
    __syncthreads();
    rh_own = rhL[i];
  };

  float un = Ug[(size_t)(b * T_SZ) * R_DIM + i];
  float sxn = SXg[b * T_SZ];

#pragma unroll 1
  for (int t = 0; t < T_SZ; t++) {
    float u = un, sxv = sxn;
    if (t < T_SZ - 1) {
      un = Ug[(size_t)(b * T_SZ + t + 1) * R_DIM + i];
      sxn = SXg[b * T_SZ + t + 1];
    }
    float u02 = 0.2f * u;
    if (kh == 0) rpL[i] = rOwn;
    if (tid == 0) cstL[0] = 0;
    refresh_rh();
    rhv = true;
    rOwn = rh_own;
    __syncthreads();
    if (kh == 0) rbuf[0][i] = rOwn;
    __syncthreads();
    bool rzero = zw;
#pragma unroll 1
    for (int it = 0; it < MAX_IT; it++) {
      if (!rhv) { refresh_rh(); rhv = true; }
      float mv = 0.f;
      if (!rzero) mv = mvhalf(rbuf[it & 1]);
      rzero = false;
      float rNew = softt(mv + 0.2f * rh_own + u02, 0.001f);
      if (kh == 0) {
        eL[i] = rOwn - rh_own;
        rbuf[(it & 1) ^ 1][i] = rNew;
      }
      rOwn = rNew;
      __syncthreads();
      if (!(zw && zr2)) {
        if (w == 0) {
          float2 br = hyp_bwd_cold(l6, r2v, zw ? 1 : 0, T2, h1W, lns, h2W, h3W,
                                   cS, cstL, rpL, eL, aL, xhL, wL,
                                   dx3L, dx2L, dx1L, rstdL);
          r2v = br.x;
          if (l6 == 0) flagL[0] = __float_as_int(br.y);
        }
        __syncthreads();
        int fl = flagL[0];
        zr2 = (fl & 2) != 0;
        if (fl & 1) {
          if (w == 0) {
            int z = hyp_fwd_cold(l6, r2v, zr2 ? 1 : 0, h1W, h1b, lns, lnb,
                                 h2W, h2b, h3W, h3b, aL, xhL, x2L, wL, rstdL);
            if (l6 == 0) flagL[0] = z;
          }
          __syncthreads();
          zw = flagL[0] != 0;
          rhv = false;
        }
      }
    }
    if (!rhv) { refresh_rh(); rhv = true; }
    {
      float mv = mvhalf(rbuf[MAX_IT & 1]);
      float gb = 0.8f * rOwn - mv;
      if (kh == 0) lc1 += rOwn * (5.f * gb) - 2.f * rOwn * u;
      if (zw) {
        if (kh == 0) lc2 += rOwn * rOwn;
      } else {
        float mvh = mvhalf(rhL);
        float gh = 0.8f * rh_own - mvh;
        if (kh == 0) {
          lc0 += rh_own * (5.f * gh) - 2.f * rh_own * u;
          float d = rOwn - rh_own;
          lc2 += d * d;
        }
      }
      if (tid == 0) sxa += sxv;
    }
  }

  const float inv = 1.f / (B_SZ * T_SZ);
  float t0 = wsum(lc0), t1 = wsum(lc1), t2 = wsum(lc2);
  if (l6 == 0) {
    float s = (w == 0) ? sxa : 0.f;
    atomicAdd(&out[0], (t0 + s) * inv);
    atomicAdd(&out[1], (t1 + s) * inv);
    atomicAdd(&out[2], t2 * inv);
  }
  if (kh == 0) out[3 + b * R_DIM + i] = rOwn;
  if (w == 0) out[3 + B_SZ * R_DIM + b * R2_DIM + l6] = r2v;
}

extern "C" void kernel_launch(void* const* d_in, const int* in_sizes, int n_in,
                              void* d_out, int out_size, void* d_ws, size_t ws_size,
                              hipStream_t stream) {
  const float* X = (const float*)d_in[0];
  const float* decW = (const float*)d_in[1];
  const float* decb = (const float*)d_in[2];
  const float* temporal = (const float*)d_in[3];
  const float* h1W = (const float*)d_in[4];
  const float* h1b = (const float*)d_in[5];
  const float* lns = (const float*)d_in[6];
  const float* lnb = (const float*)d_in[7];
  const float* h2W = (const float*)d_in[8];
  const float* h2b = (const float*)d_in[9];
  const float* h3W = (const float*)d_in[10];
  const float* h3b = (const float*)d_in[11];
  float* ws = (float*)d_ws;  // ~2.3 MiB used
  float* out = (float*)d_out;

  k_prep<<<529, 256, 0, stream>>>(X, decb, decW, h1W, h1b, lns, lnb,
                                  h2W, h2b, h3W, h3b, ws, out);
  k_main<<<B_SZ, 256, 0, stream>>>(ws, temporal, h1W, h1b, lns, lnb,
                                   h2W, h2b, h3W, h3b, out);
  k_ista<<<B_SZ * T_SZ / 4, 256, 0, stream>>>(ws, out);
}

// Round 12
// 260.661 us; speedup vs baseline: 1.0143x; 1.0038x over previous
//
#include <hip/hip_runtime.h>
#include <cstdint>
#include <cstddef>

// Problem constants
#define R_DIM   128
#define R2_DIM  64
#define MIX     32
#define IN_DIM  512
#define HID     256
#define B_SZ    256
#define T_SZ    16
#define MAX_IT  12

// Workspace layout (float offsets)
#define OFF_G    0           // 16384 floats (row-major 128x128, M = 0.8I - 0.2G, symmetric)
#define OFF_U    24576       // 4096*128
#define OFF_SX   548864      // 4096
#define OFF_FLAG 552960      // 1 int: 1 = absorbing fast mode (hypernet(0) == 0)
#define OFF_LOSS 552961      // 48 floats: [3][16] per-t loss partials (fast mode)
#define OFF_CNT  553012      // 1 int: fast-path completion counter

__device__ __forceinline__ float softt(float v, float lam) {
  float a = fabsf(v) - lam;
  return a > 0.f ? (v > 0.f ? a : -a) : 0.f;
}

__device__ __forceinline__ float rdlane(float v, int lane) {
  int i = __builtin_amdgcn_readlane(__float_as_int(v), lane);
  return __int_as_float(i);
}

__device__ __forceinline__ float wsum_all(float v) {  // within wave64
#pragma unroll
  for (int off = 32; off; off >>= 1) v += __shfl_xor(v, off, 64);
  return v;
}

__device__ __forceinline__ float wsum(float v) {  // lane 0 of each wave
#pragma unroll
  for (int off = 32; off; off >>= 1) v += __shfl_down(v, off, 64);
  return v;
}

// Sum of the two kh-half partials held by lanes l and l+32 (a=b form validated
// green in R3/R5/R6 benches). Pure VALU, no LDS round-trip.
__device__ __forceinline__ float pairsum32(float pm) {
  float a = pm, b = pm;
  asm volatile("v_permlane32_swap_b32 %0, %1" : "+v"(a), "+v"(b));
  return a + b;
}

// =============== COLD hypernet path: __noinline__, 64-lane (wave 0 only) ======
__device__ void ensure_c_dev(int l, const float* __restrict__ T2, float* cS,
                             int* cstL, const float* rpL) {
  if (cstL[0]) return;  // wave-0-only caller: uniform
  for (int p = l; p < MIX * R_DIM; p += 64) {
    const float* row = T2 + (size_t)p * R_DIM;
    float acc = 0.f;
    for (int j4 = 0; j4 < R_DIM / 4; j4++) {
      float4 w4 = *(const float4*)(row + j4 * 4);
      float4 r4 = *(const float4*)(rpL + j4 * 4);
      acc += w4.x * r4.x + w4.y * r4.y + w4.z * r4.z + w4.w * r4.w;
    }
    cS[(p >> 7) * 129 + (p & 127)] = acc;
  }
  if (l == 0) cstL[0] = 1;
}

__device__ __noinline__ float2 rhat_cold(int l, const float* __restrict__ T2,
                                         float* cS, int* cstL,
                                         const float* rpL, const float* wL) {
  ensure_c_dev(l, T2, cS, cstL, rpL);
  float a0 = 0.f, a1 = 0.f;
#pragma unroll
  for (int m4 = 0; m4 < 8; m4++) {
    float4 w4 = *(const float4*)&wL[m4 * 4];
    int mb = m4 * 4;
    a0 += w4.x * cS[(mb + 0) * 129 + l] + w4.y * cS[(mb + 1) * 129 + l] +
          w4.z * cS[(mb + 2) * 129 + l] + w4.w * cS[(mb + 3) * 129 + l];
    a1 += w4.x * cS[(mb + 0) * 129 + 64 + l] + w4.y * cS[(mb + 1) * 129 + 64 + l] +
          w4.z * cS[(mb + 2) * 129 + 64 + l] + w4.w * cS[(mb + 3) * 129 + 64 + l];
  }
  return make_float2(a0, a1);
}

// returns 1 if w == 0 (zw)
__device__ __noinline__ int hyp_fwd_cold(
    int l, float r2v, int zr2,
    const float* __restrict__ h1W, const float* __restrict__ h1b,
    const float* __restrict__ lns, const float* __restrict__ lnb,
    const float* __restrict__ h2W, const float* __restrict__ h2b,
    const float* __restrict__ h3W, const float* __restrict__ h3b,
    float* aL, float* xhL, float* x2L, float* wL, float* rstdL) {
  float x1[4];
#pragma unroll
  for (int q = 0; q < 4; q++) x1[q] = h1b[l + 64 * q];
  if (!zr2) {
    for (int k = 0; k < R2_DIM; k++) {
      float rk = rdlane(r2v, k);
      if (rk != 0.f) {
#pragma unroll
        for (int q = 0; q < 4; q++) x1[q] += rk * h1W[k * HID + l + 64 * q];
      }
    }
  }
  float s1 = x1[0] + x1[1] + x1[2] + x1[3];
  float s2 = x1[0] * x1[0] + x1[1] * x1[1] + x1[2] * x1[2] + x1[3] * x1[3];
  s1 = wsum_all(s1); s2 = wsum_all(s2);
  float mu = s1 * (1.f / HID);
  float var = s2 * (1.f / HID) - mu * mu;
  float rstd = rsqrtf(var + 1e-6f);
  if (l == 0) rstdL[0] = rstd;
  bool anz = false;
#pragma unroll
  for (int q = 0; q < 4; q++) {
    float xh = (x1[q] - mu) * rstd;
    xhL[l + 64 * q] = xh;
    float y = xh * lns[l + 64 * q] + lnb[l + 64 * q];
    float a = (y > 0.f) ? y : expm1f(y);
    aL[l + 64 * q] = a;
    anz |= (a != 0.f);
  }
  bool za = (__ballot(anz) == 0ull);
  float x2[4];
#pragma unroll
  for (int q = 0; q < 4; q++) x2[q] = h2b[l + 64 * q];
  if (!za) {
    for (int k4 = 0; k4 < HID / 4; k4++) {
      float4 a4 = *(const float4*)&aL[k4 * 4];
#pragma unroll
      for (int c = 0; c < 4; c++) {
        float ac = (&a4.x)[c];
        int k = k4 * 4 + c;
#pragma unroll
        for (int q = 0; q < 4; q++) x2[q] += ac * h2W[(size_t)k * HID + l + 64 * q];
      }
    }
  }
  bool x2nz = false;
#pragma unroll
  for (int q = 0; q < 4; q++) { x2L[l + 64 * q] = x2[q]; x2nz |= (x2[q] != 0.f); }
  bool zx2 = (__ballot(x2nz) == 0ull);
  int m = l & 31, kh = l >> 5;
  float p = 0.f;
  if (!zx2) {
    for (int kk = 0; kk < 128; kk++) {
      int k = kh * 128 + kk;
      p += x2L[k] * h3W[k * MIX + m];
    }
  }
  p += __shfl_xor(p, 32, 64);
  float wv = 0.f;
  if (l < 32) { wv = fmaxf(h3b[l] + p, 0.f); wL[l] = wv; }
  return (__ballot(wv != 0.f) == 0ull) ? 1 : 0;
}

// returns: .x = new r2, .y = flags bitcast (bit0 changed, bit1 zr2)
__device__ __noinline__ float2 hyp_bwd_cold(
    int l, float r2v, int zw,
    const float* __restrict__ T2,
    const float* __restrict__ h1W, const float* __restrict__ lns,
    const float* __restrict__ h2W, const float* __restrict__ h3W,
    float* cS, int* cstL, const float* rpL, const float* eL,
    const float* aL, const float* xhL, const float* wL,
    float* dx3L, float* dx2L, float* dx1L, const float* rstdL) {
  bool zd3 = true;
  if (!zw) {
    ensure_c_dev(l, T2, cS, cstL, rpL);
    int m = l & 31, ih = l >> 5;
    float p = 0.f;
    for (int ii = 0; ii < 64; ii++) {
      int i = ih * 64 + ii;
      p += eL[i] * cS[m * 129 + i];
    }
    p += __shfl_xor(p, 32, 64);
    float d3 = 0.f;
    if (l < 32) { d3 = (wL[l] > 0.f) ? (-2.f * p) : 0.f; dx3L[l] = d3; }
    zd3 = (__ballot(d3 != 0.f) == 0ull);
  }
  float g = 0.f;
  if (!zd3) {
    float rstd = rstdL[0];
    float dx2[4] = {0.f, 0.f, 0.f, 0.f};
#pragma unroll
    for (int m4 = 0; m4 < 8; m4++) {
      float4 d4 = *(const float4*)&dx3L[m4 * 4];
#pragma unroll
      for (int q = 0; q < 4; q++) {
        const float* r3 = h3W + (size_t)(l + 64 * q) * MIX + m4 * 4;
        dx2[q] += d4.x * r3[0] + d4.y * r3[1] + d4.z * r3[2] + d4.w * r3[3];
      }
    }
#pragma unroll
    for (int q = 0; q < 4; q++) dx2L[l + 64 * q] = dx2[q];
    float dxh[4];
    float s1 = 0.f, s2 = 0.f;
#pragma unroll
    for (int q = 0; q < 4; q++) {
      float da = 0.f;
      const float* row = h2W + (size_t)(l + 64 * q) * HID;
      for (int k4 = 0; k4 < HID / 4; k4++) {
        float4 w4 = *(const float4*)(row + k4 * 4);
        float4 d4 = *(const float4*)&dx2L[k4 * 4];
        da += w4.x * d4.x + w4.y * d4.y + w4.z * d4.z + w4.w * d4.w;
      }
      float a = aL[l + 64 * q];
      float dy = da * (a > 0.f ? 1.f : (a + 1.f));
      dxh[q] = dy * lns[l + 64 * q];
      s1 += dxh[q]; s2 += dxh[q] * xhL[l + 64 * q];
    }
    s1 = wsum_all(s1); s2 = wsum_all(s2);
#pragma unroll
    for (int q = 0; q < 4; q++) {
      float dx1 = rstd * (dxh[q] - s1 * (1.f / HID) - xhL[l + 64 * q] * (s2 * (1.f / HID)));
      dx1L[l + 64 * q] = dx1;
    }
    const float* row1 = h1W + (size_t)l * HID;
    for (int j4 = 0; j4 < HID / 4; j4++) {
      float4 w4 = *(const float4*)(row1 + j4 * 4);
      float4 d4 = *(const float4*)&dx1L[j4 * 4];
      g += w4.x * d4.x + w4.y * d4.y + w4.z * d4.z + w4.w * d4.w;
    }
  }
  float r2n = softt(r2v - 0.1f * g, 0.001f);
  int fl = 0;
  if (__ballot(r2n != r2v) != 0ull) fl |= 1;
  if (__ballot(r2n != 0.f) == 0ull) fl |= 2;
  return make_float2(r2n, __int_as_float(fl));
}

// ---------------- prep: G (folded), U, SX, flag, zero loss slots --------------
__global__ __launch_bounds__(256) void k_prep(const float* __restrict__ X,
                                              const float* __restrict__ decb,
                                              const float* __restrict__ decW,
                                              const float* __restrict__ h1W,
                                              const float* __restrict__ h1b,
                                              const float* __restrict__ lns,
                                              const float* __restrict__ lnb,
                                              const float* __restrict__ h2W,
                                              const float* __restrict__ h2b,
                                              const float* __restrict__ h3W,
                                              const float* __restrict__ h3b,
                                              float* __restrict__ ws,
                                              float* __restrict__ out) {
  __shared__ __align__(16) float As[8][IN_DIM];    // 16 KB
  __shared__ float scr[256];
  __shared__ __align__(16) float aF[HID], xhF[HID], x2F[HID];
  __shared__ __align__(16) float wF[MIX];
  __shared__ float rsF[1];
  float* G = ws + OFF_G;
  float* U = ws + OFF_U;
  float* SX = ws + OFF_SX;
  const int tid = threadIdx.x;
  const int bx = blockIdx.x;

  if (bx == 528) {  // absorbing-state probe, wave 0 only
    if (tid < 64) {
      int z = hyp_fwd_cold(tid, 0.f, 1, h1W, h1b, lns, lnb, h2W, h2b, h3W, h3b,
                           aF, xhF, x2F, wF, rsF);
      if (tid == 0) ((int*)(ws + OFF_FLAG))[0] = z;
    }
    return;
  }
  const bool isG = (bx >= 512);

  if (bx == 0 && tid < 3) out[tid] = 0.f;             // loss accumulators (serial)
  if (bx == 0 && tid < 48) ws[OFF_LOSS + tid] = 0.f;  // loss slots (fast)
  if (bx == 0 && tid == 48) ((int*)(ws + OFF_CNT))[0] = 0;  // completion counter

  // ---- stage A rows (X - b, or decW rows for G blocks) + SX partials ----
  {
    int g = tid >> 5;             // row 0..7
    int f0 = tid & 31;            // float4 slot base
    if (!isG) {
      int row0 = bx * 8;
      float p = 0.f;
#pragma unroll
      for (int q = 0; q < 4; q++) {
        int f4 = f0 + 32 * q;
        float4 xv = *reinterpret_cast<const float4*>(X + (size_t)(row0 + g) * IN_DIM + f4 * 4);
        float4 bv = *reinterpret_cast<const float4*>(decb + f4 * 4);
        float4 v = make_float4(xv.x - bv.x, xv.y - bv.y, xv.z - bv.z, xv.w - bv.w);
        *reinterpret_cast<float4*>(&As[g][f4 * 4]) = v;
        p += v.x * v.x + v.y * v.y + v.z * v.z + v.w * v.w;
      }
      scr[tid] = p;
    } else {
      int row0 = (bx - 512) * 8;
#pragma unroll
      for (int q = 0; q < 4; q++) {
        int f4 = f0 + 32 * q;
        float4 v = *reinterpret_cast<const float4*>(decW + (size_t)(row0 + g) * IN_DIM + f4 * 4);
        *reinterpret_cast<float4*>(&As[g][f4 * 4]) = v;
      }
    }
  }
  __syncthreads();
  if (!isG && tid < 8) {
    float s = 0.f;
#pragma unroll
    for (int q = 0; q < 32; q++) s += scr[tid * 32 + q];
    SX[bx * 8 + tid] = s;
  }

  const int j = tid & 127;        // output column
  const int gh = tid >> 7;        // row-half (4 rows each)
  float acc[4] = {0.f, 0.f, 0.f, 0.f};
  const float* wrow = decW + (size_t)j * IN_DIM;

#pragma unroll 4
  for (int k4 = 0; k4 < IN_DIM / 4; k4++) {
    float4 w4 = *reinterpret_cast<const float4*>(wrow + k4 * 4);
#pragma unroll
    for (int gi = 0; gi < 4; gi++) {
      // gg uniform per wave -> As reads are broadcasts
      float4 a4 = *reinterpret_cast<const float4*>(&As[gh * 4 + gi][k4 * 4]);
      acc[gi] += w4.x * a4.x + w4.y * a4.y + w4.z * a4.z + w4.w * a4.w;
    }
  }

  if (!isG) {
    int row0 = bx * 8;
#pragma unroll
    for (int gi = 0; gi < 4; gi++)
      U[(size_t)(row0 + gh * 4 + gi) * R_DIM + j] = acc[gi];
  } else {
    int row0 = (bx - 512) * 8;
#pragma unroll
    for (int gi = 0; gi < 4; gi++) {
      int rr = row0 + gh * 4 + gi;
      float gv = -0.2f * acc[gi];            // fold M = 0.8I - 0.2G
      if (rr == j) gv += 0.8f;
      G[(size_t)rr * R_DIM + j] = gv;
    }
  }
}

// ---------------- FAST path: one block per (b,t); absorbing state only -------
// Bit-exact R5 body (the session's proven 90us optimum) + fused finalization
// (green in R7/R8/R10/R11). NO pins, NO launch_bounds games: 7 variants
// (R6-R11) that fought the allocator's ~52-VGPR target all lost (remat ->
// 90us is benign; pins -> spill -> 143-150us; col-sharing -> VGPR 120+ ->
// occupancy collapse). At 16 blocks/CU this structure is LDS-pipe/latency
// bound at ~90us; that is the empirical optimum of the design space.
__global__ __launch_bounds__(256, 4) void k_ista(float* __restrict__ ws,
                                                 float* __restrict__ out) {
  if (((const int*)(ws + OFF_FLAG))[0] == 0) return;  // cold mode: serial path
  __shared__ __align__(16) float rbuf[2][R_DIM];
  __shared__ float scr[8];

  const int tid = threadIdx.x;
  const int w = tid >> 6;
  const int l6 = tid & 63;
  const int i = (w << 5) + (l6 & 31);
  const int kh = l6 >> 5;
  const int bt = blockIdx.x;
  const int b = bt >> 4;
  const int t = bt & 15;
  const float* Gg = ws + OFF_G;
  const float* Ug = ws + OFF_U;

  float Ga[64];
#pragma unroll
  for (int kk = 0; kk < 64; kk++)
    Ga[kk] = Gg[(size_t)(kh * 64 + kk) * R_DIM + i];

  const float u = Ug[(size_t)bt * R_DIM + i];
  const float u02 = 0.2f * u;

  auto mvhalf = [&](const float* vptr) {
    const float* vp = vptr + (kh << 6);
    float p0 = 0.f, p1 = 0.f, p2 = 0.f, p3 = 0.f;
#pragma unroll
    for (int k4 = 0; k4 < 16; k4++) {
      float4 v4 = *reinterpret_cast<const float4*>(vp + k4 * 4);
      p0 += v4.x * Ga[k4 * 4 + 0];
      p1 += v4.y * Ga[k4 * 4 + 1];
      p2 += v4.z * Ga[k4 * 4 + 2];
      p3 += v4.w * Ga[k4 * 4 + 3];
    }
    float pm = (p0 + p1) + (p2 + p3);
    return pairsum32(pm);
  };

  // it = 0: r_prev = warm = 0 -> r = softt(0.2*u)
  float r = softt(u02, 0.001f);
  if (kh == 0) rbuf[1][i] = r;
  __syncthreads();
#pragma unroll 1
  for (int it = 1; it < MAX_IT; it++) {
    float mv = mvhalf(rbuf[it & 1]);
    r = softt(mv + u02, 0.001f);
    if (kh == 0) rbuf[(it & 1) ^ 1][i] = r;   // write buffer != read buffer
    __syncthreads();
  }
  // last write (it=11) went to rbuf[0]; barrier done.
  float mvf = mvhalf(rbuf[0]);
  float gb = 0.8f * r - mvf;                   // = 0.2*(G r)_i
  float l1 = (kh == 0) ? (r * (5.f * gb) - 2.f * r * u) : 0.f;
  float l2 = (kh == 0) ? (r * r) : 0.f;
  l1 = wsum(l1); l2 = wsum(l2);
  if (l6 == 0) { scr[w * 2 + 0] = l1; scr[w * 2 + 1] = l2; }
  __syncthreads();
  if (tid == 0) {
    float s1 = scr[0] + scr[2] + scr[4] + scr[6];
    float s2 = scr[1] + scr[3] + scr[5] + scr[7];
    float sx = ws[OFF_SX + bt];
    float* loss = ws + OFF_LOSS;
    atomicAdd(&loss[0 * 16 + t], sx);          // spat_rhat: decode(0) vs x
    atomicAdd(&loss[1 * 16 + t], s1 + sx);     // spat_rbar
    atomicAdd(&loss[2 * 16 + t], s2);          // temp loss: ||r - 0||^2
    // fused finalization: last block reduces the 48 slots (replaces k_fin)
    __threadfence();
    int old = atomicAdd((int*)(ws + OFF_CNT), 1);
    if (old == B_SZ * T_SZ - 1) {
      float s[3] = {0.f, 0.f, 0.f};
#pragma unroll
      for (int k = 0; k < 3; k++)
        for (int tt = 0; tt < 16; tt++)
          s[k] += atomicAdd(&loss[k * 16 + tt], 0.f);  // coherent read
      const float inv = 1.f / (B_SZ * T_SZ);
      out[0] = s[0] * inv; out[1] = s[1] * inv; out[2] = s[2] * inv;
    }
  }
  if (t == T_SZ - 1 && kh == 0) out[3 + b * R_DIM + i] = r;
  if (t == 0 && w == 0) out[3 + B_SZ * R_DIM + b * R2_DIM + l6] = 0.f;
}

// ---------------- SERIAL fallback: bit-faithful R0 body (proven green) -------
__global__ __launch_bounds__(256, 1) void k_main(
    float* __restrict__ ws, const float* __restrict__ T2,
    const float* __restrict__ h1W, const float* __restrict__ h1b,
    const float* __restrict__ lns, const float* __restrict__ lnb,
    const float* __restrict__ h2W, const float* __restrict__ h2b,
    const float* __restrict__ h3W, const float* __restrict__ h3b,
    float* __restrict__ out) {
  if (((const int*)(ws + OFF_FLAG))[0] != 0) return;  // fast path covers
  __shared__ __align__(16) float rbuf[2][R_DIM];
  __shared__ __align__(16) float rhL[R_DIM];
  __shared__ __align__(16) float cS[MIX * 129];
  __shared__ __align__(16) float aL[HID];
  __shared__ __align__(16) float xhL[HID];
  __shared__ __align__(16) float x2L[HID];
  __shared__ __align__(16) float dx1L[HID];
  __shared__ __align__(16) float dx2L[HID];
  __shared__ __align__(16) float wL[MIX];
  __shared__ __align__(16) float dx3L[MIX];
  __shared__ __align__(16) float eL[R_DIM];
  __shared__ __align__(16) float rpL[R_DIM];
  __shared__ float rstdL[1];
  __shared__ int cstL[1];
  __shared__ int flagL[1];

  const int tid = threadIdx.x;
  const int w = tid >> 6;
  const int l6 = tid & 63;
  const int i = (w << 5) + (l6 & 31);
  const int kh = l6 >> 5;
  const int b = blockIdx.x;
  const float* Gg = ws + OFF_G;
  const float* Ug = ws + OFF_U;
  const float* SXg = ws + OFF_SX;

  float r2v = 0.f;
  bool zr2 = true, rhv;

  if (w == 0) {
    int z = hyp_fwd_cold(l6, 0.f, 1, h1W, h1b, lns, lnb, h2W, h2b, h3W, h3b,
                         aL, xhL, x2L, wL, rstdL);
    if (l6 == 0) flagL[0] = z;
  }
  __syncthreads();
  bool zw = flagL[0] != 0;

  float Ga[64];
#pragma unroll
  for (int kk = 0; kk < 64; kk++)
    Ga[kk] = Gg[(size_t)(kh * 64 + kk) * R_DIM + i];

  float rOwn = 0.f;
  float lc0 = 0.f, lc1 = 0.f, lc2 = 0.f, sxa = 0.f;

  auto mvhalf = [&](const float* vptr) {
    const float* vp = vptr + (kh << 6);
    float p0 = 0.f, p1 = 0.f, p2 = 0.f, p3 = 0.f;
#pragma unroll
    for (int k4 = 0; k4 < 16; k4++) {
      float4 v4 = *reinterpret_cast<const float4*>(vp + k4 * 4);
      p0 += v4.x * Ga[k4 * 4 + 0];
      p1 += v4.y * Ga[k4 * 4 + 1];
      p2 += v4.z * Ga[k4 * 4 + 2];
      p3 += v4.w * Ga[k4 * 4 + 3];
    }
    float pm = (p0 + p1) + (p2 + p3);
    return pm + __shfl_xor(pm, 32, 64);
  };

  float rh_own = 0.f;
  auto refresh_rh = [&]() {
    if (zw) { rh_own = 0.f; return; }
    __syncthreads();
    if (w == 0) {
      float2 rr = rhat_cold(l6, T2, cS, cstL, rpL, wL);
      rhL[l6] = rr.x; rhL[64 + l6] = rr.y;
    }
    __syncthreads();
    rh_own = rhL[i];
  };

  float un = Ug[(size_t)(b * T_SZ) * R_DIM + i];
  float sxn = SXg[b * T_SZ];

#pragma unroll 1
  for (int t = 0; t < T_SZ; t++) {
    float u = un, sxv = sxn;
    if (t < T_SZ - 1) {
      un = Ug[(size_t)(b * T_SZ + t + 1) * R_DIM + i];
      sxn = SXg[b * T_SZ + t + 1];
    }
    float u02 = 0.2f * u;
    if (kh == 0) rpL[i] = rOwn;
    if (tid == 0) cstL[0] = 0;
    refresh_rh();
    rhv = true;
    rOwn = rh_own;
    __syncthreads();
    if (kh == 0) rbuf[0][i] = rOwn;
    __syncthreads();
    bool rzero = zw;
#pragma unroll 1
    for (int it = 0; it < MAX_IT; it++) {
      if (!rhv) { refresh_rh(); rhv = true; }
      float mv = 0.f;
      if (!rzero) mv = mvhalf(rbuf[it & 1]);
      rzero = false;
      float rNew = softt(mv + 0.2f * rh_own + u02, 0.001f);
      if (kh == 0) {
        eL[i] = rOwn - rh_own;
        rbuf[(it & 1) ^ 1][i] = rNew;
      }
      rOwn = rNew;
      __syncthreads();
      if (!(zw && zr2)) {
        if (w == 0) {
          float2 br = hyp_bwd_cold(l6, r2v, zw ? 1 : 0, T2, h1W, lns, h2W, h3W,
                                   cS, cstL, rpL, eL, aL, xhL, wL,
                                   dx3L, dx2L, dx1L, rstdL);
          r2v = br.x;
          if (l6 == 0) flagL[0] = __float_as_int(br.y);
        }
        __syncthreads();
        int fl = flagL[0];
        zr2 = (fl & 2) != 0;
        if (fl & 1) {
          if (w == 0) {
            int z = hyp_fwd_cold(l6, r2v, zr2 ? 1 : 0, h1W, h1b, lns, lnb,
                                 h2W, h2b, h3W, h3b, aL, xhL, x2L, wL, rstdL);
            if (l6 == 0) flagL[0] = z;
          }
          __syncthreads();
          zw = flagL[0] != 0;
          rhv = false;
        }
      }
    }
    if (!rhv) { refresh_rh(); rhv = true; }
    {
      float mv = mvhalf(rbuf[MAX_IT & 1]);
      float gb = 0.8f * rOwn - mv;
      if (kh == 0) lc1 += rOwn * (5.f * gb) - 2.f * rOwn * u;
      if (zw) {
        if (kh == 0) lc2 += rOwn * rOwn;
      } else {
        float mvh = mvhalf(rhL);
        float gh = 0.8f * rh_own - mvh;
        if (kh == 0) {
          lc0 += rh_own * (5.f * gh) - 2.f * rh_own * u;
          float d = rOwn - rh_own;
          lc2 += d * d;
        }
      }
      if (tid == 0) sxa += sxv;
    }
  }

  const float inv = 1.f / (B_SZ * T_SZ);
  float t0 = wsum(lc0), t1 = wsum(lc1), t2 = wsum(lc2);
  if (l6 == 0) {
    float s = (w == 0) ? sxa : 0.f;
    atomicAdd(&out[0], (t0 + s) * inv);
    atomicAdd(&out[1], (t1 + s) * inv);
    atomicAdd(&out[2], t2 * inv);
  }
  if (kh == 0) out[3 + b * R_DIM + i] = rOwn;
  if (w == 0) out[3 + B_SZ * R_DIM + b * R2_DIM + l6] = r2v;
}

extern "C" void kernel_launch(void* const* d_in, const int* in_sizes, int n_in,
                              void* d_out, int out_size, void* d_ws, size_t ws_size,
                              hipStream_t stream) {
  const float* X = (const float*)d_in[0];
  const float* decW = (const float*)d_in[1];
  const float* decb = (const float*)d_in[2];
  const float* temporal = (const float*)d_in[3];
  const float* h1W = (const float*)d_in[4];
  const float* h1b = (const float*)d_in[5];
  const float* lns = (const float*)d_in[6];
  const float* lnb = (const float*)d_in[7];
  const float* h2W = (const float*)d_in[8];
  const float* h2b = (const float*)d_in[9];
  const float* h3W = (const float*)d_in[10];
  const float* h3b = (const float*)d_in[11];
  float* ws = (float*)d_ws;  // ~2.22 MiB used
  float* out = (float*)d_out;

  k_prep<<<529, 256, 0, stream>>>(X, decb, decW, h1W, h1b, lns, lnb,
                                  h2W, h2b, h3W, h3b, ws, out);
  k_main<<<B_SZ, 256, 0, stream>>>(ws, temporal, h1W, h1b, lns, lnb,
                                   h2W, h2b, h3W, h3b, out);
  k_ista<<<B_SZ * T_SZ, 256, 0, stream>>>(ws, out);
}

// Round 13
// 209.162 us; speedup vs baseline: 1.2640x; 1.2462x over previous
//
#include <hip/hip_runtime.h>
#include <cstdint>
#include <cstddef>

// Problem constants
#define R_DIM   128
#define R2_DIM  64
#define MIX     32
#define IN_DIM  512
#define HID     256
#define B_SZ    256
#define T_SZ    16
#define MAX_IT  12

// Workspace layout (float offsets)
#define OFF_G    0           // 16384 floats (row-major 128x128, M = 0.8I - 0.2G, symmetric)
#define OFF_U    24576       // 4096*128
#define OFF_SX   548864      // 4096
#define OFF_FLAG 552960      // 1 int: 1 = absorbing fast mode (hypernet(0) == 0)
#define OFF_LOSS 552961      // 48 floats: [3][16] per-t loss partials (fast mode)

__device__ __forceinline__ float softt(float v, float lam) {
  float a = fabsf(v) - lam;
  return a > 0.f ? (v > 0.f ? a : -a) : 0.f;
}

__device__ __forceinline__ float rdlane(float v, int lane) {
  int i = __builtin_amdgcn_readlane(__float_as_int(v), lane);
  return __int_as_float(i);
}

__device__ __forceinline__ float wsum_all(float v) {  // within wave64
#pragma unroll
  for (int off = 32; off; off >>= 1) v += __shfl_xor(v, off, 64);
  return v;
}

__device__ __forceinline__ float wsum(float v) {  // lane 0 of each wave
#pragma unroll
  for (int off = 32; off; off >>= 1) v += __shfl_down(v, off, 64);
  return v;
}

// Sum of the two kh-half partials held by lanes l and l+32 (a=b form validated
// green in R3/R5/R6 benches). Pure VALU, no LDS round-trip.
__device__ __forceinline__ float pairsum32(float pm) {
  float a = pm, b = pm;
  asm volatile("v_permlane32_swap_b32 %0, %1" : "+v"(a), "+v"(b));
  return a + b;
}

// =============== COLD hypernet path: __noinline__, 64-lane (wave 0 only) ======
__device__ void ensure_c_dev(int l, const float* __restrict__ T2, float* cS,
                             int* cstL, const float* rpL) {
  if (cstL[0]) return;  // wave-0-only caller: uniform
  for (int p = l; p < MIX * R_DIM; p += 64) {
    const float* row = T2 + (size_t)p * R_DIM;
    float acc = 0.f;
    for (int j4 = 0; j4 < R_DIM / 4; j4++) {
      float4 w4 = *(const float4*)(row + j4 * 4);
      float4 r4 = *(const float4*)(rpL + j4 * 4);
      acc += w4.x * r4.x + w4.y * r4.y + w4.z * r4.z + w4.w * r4.w;
    }
    cS[(p >> 7) * 129 + (p & 127)] = acc;
  }
  if (l == 0) cstL[0] = 1;
}

__device__ __noinline__ float2 rhat_cold(int l, const float* __restrict__ T2,
                                         float* cS, int* cstL,
                                         const float* rpL, const float* wL) {
  ensure_c_dev(l, T2, cS, cstL, rpL);
  float a0 = 0.f, a1 = 0.f;
#pragma unroll
  for (int m4 = 0; m4 < 8; m4++) {
    float4 w4 = *(const float4*)&wL[m4 * 4];
    int mb = m4 * 4;
    a0 += w4.x * cS[(mb + 0) * 129 + l] + w4.y * cS[(mb + 1) * 129 + l] +
          w4.z * cS[(mb + 2) * 129 + l] + w4.w * cS[(mb + 3) * 129 + l];
    a1 += w4.x * cS[(mb + 0) * 129 + 64 + l] + w4.y * cS[(mb + 1) * 129 + 64 + l] +
          w4.z * cS[(mb + 2) * 129 + 64 + l] + w4.w * cS[(mb + 3) * 129 + 64 + l];
  }
  return make_float2(a0, a1);
}

// returns 1 if w == 0 (zw)
__device__ __noinline__ int hyp_fwd_cold(
    int l, float r2v, int zr2,
    const float* __restrict__ h1W, const float* __restrict__ h1b,
    const float* __restrict__ lns, const float* __restrict__ lnb,
    const float* __restrict__ h2W, const float* __restrict__ h2b,
    const float* __restrict__ h3W, const float* __restrict__ h3b,
    float* aL, float* xhL, float* x2L, float* wL, float* rstdL) {
  float x1[4];
#pragma unroll
  for (int q = 0; q < 4; q++) x1[q] = h1b[l + 64 * q];
  if (!zr2) {
    for (int k = 0; k < R2_DIM; k++) {
      float rk = rdlane(r2v, k);
      if (rk != 0.f) {
#pragma unroll
        for (int q = 0; q < 4; q++) x1[q] += rk * h1W[k * HID + l + 64 * q];
      }
    }
  }
  float s1 = x1[0] + x1[1] + x1[2] + x1[3];
  float s2 = x1[0] * x1[0] + x1[1] * x1[1] + x1[2] * x1[2] + x1[3] * x1[3];
  s1 = wsum_all(s1); s2 = wsum_all(s2);
  float mu = s1 * (1.f / HID);
  float var = s2 * (1.f / HID) - mu * mu;
  float rstd = rsqrtf(var + 1e-6f);
  if (l == 0) rstdL[0] = rstd;
  bool anz = false;
#pragma unroll
  for (int q = 0; q < 4; q++) {
    float xh = (x1[q] - mu) * rstd;
    xhL[l + 64 * q] = xh;
    float y = xh * lns[l + 64 * q] + lnb[l + 64 * q];
    float a = (y > 0.f) ? y : expm1f(y);
    aL[l + 64 * q] = a;
    anz |= (a != 0.f);
  }
  bool za = (__ballot(anz) == 0ull);
  float x2[4];
#pragma unroll
  for (int q = 0; q < 4; q++) x2[q] = h2b[l + 64 * q];
  if (!za) {
    for (int k4 = 0; k4 < HID / 4; k4++) {
      float4 a4 = *(const float4*)&aL[k4 * 4];
#pragma unroll
      for (int c = 0; c < 4; c++) {
        float ac = (&a4.x)[c];
        int k = k4 * 4 + c;
#pragma unroll
        for (int q = 0; q < 4; q++) x2[q] += ac * h2W[(size_t)k * HID + l + 64 * q];
      }
    }
  }
  bool x2nz = false;
#pragma unroll
  for (int q = 0; q < 4; q++) { x2L[l + 64 * q] = x2[q]; x2nz |= (x2[q] != 0.f); }
  bool zx2 = (__ballot(x2nz) == 0ull);
  int m = l & 31, kh = l >> 5;
  float p = 0.f;
  if (!zx2) {
    for (int kk = 0; kk < 128; kk++) {
      int k = kh * 128 + kk;
      p += x2L[k] * h3W[k * MIX + m];
    }
  }
  p += __shfl_xor(p, 32, 64);
  float wv = 0.f;
  if (l < 32) { wv = fmaxf(h3b[l] + p, 0.f); wL[l] = wv; }
  return (__ballot(wv != 0.f) == 0ull) ? 1 : 0;
}

// returns: .x = new r2, .y = flags bitcast (bit0 changed, bit1 zr2)
__device__ __noinline__ float2 hyp_bwd_cold(
    int l, float r2v, int zw,
    const float* __restrict__ T2,
    const float* __restrict__ h1W, const float* __restrict__ lns,
    const float* __restrict__ h2W, const float* __restrict__ h3W,
    float* cS, int* cstL, const float* rpL, const float* eL,
    const float* aL, const float* xhL, const float* wL,
    float* dx3L, float* dx2L, float* dx1L, const float* rstdL) {
  bool zd3 = true;
  if (!zw) {
    ensure_c_dev(l, T2, cS, cstL, rpL);
    int m = l & 31, ih = l >> 5;
    float p = 0.f;
    for (int ii = 0; ii < 64; ii++) {
      int i = ih * 64 + ii;
      p += eL[i] * cS[m * 129 + i];
    }
    p += __shfl_xor(p, 32, 64);
    float d3 = 0.f;
    if (l < 32) { d3 = (wL[l] > 0.f) ? (-2.f * p) : 0.f; dx3L[l] = d3; }
    zd3 = (__ballot(d3 != 0.f) == 0ull);
  }
  float g = 0.f;
  if (!zd3) {
    float rstd = rstdL[0];
    float dx2[4] = {0.f, 0.f, 0.f, 0.f};
#pragma unroll
    for (int m4 = 0; m4 < 8; m4++) {
      float4 d4 = *(const float4*)&dx3L[m4 * 4];
#pragma unroll
      for (int q = 0; q < 4; q++) {
        const float* r3 = h3W + (size_t)(l + 64 * q) * MIX + m4 * 4;
        dx2[q] += d4.x * r3[0] + d4.y * r3[1] + d4.z * r3[2] + d4.w * r3[3];
      }
    }
#pragma unroll
    for (int q = 0; q < 4; q++) dx2L[l + 64 * q] = dx2[q];
    float dxh[4];
    float s1 = 0.f, s2 = 0.f;
#pragma unroll
    for (int q = 0; q < 4; q++) {
      float da = 0.f;
      const float* row = h2W + (size_t)(l + 64 * q) * HID;
      for (int k4 = 0; k4 < HID / 4; k4++) {
        float4 w4 = *(const float4*)(row + k4 * 4);
        float4 d4 = *(const float4*)&dx2L[k4 * 4];
        da += w4.x * d4.x + w4.y * d4.y + w4.z * d4.z + w4.w * d4.w;
      }
      float a = aL[l + 64 * q];
      float dy = da * (a > 0.f ? 1.f : (a + 1.f));
      dxh[q] = dy * lns[l + 64 * q];
      s1 += dxh[q]; s2 += dxh[q] * xhL[l + 64 * q];
    }
    s1 = wsum_all(s1); s2 = wsum_all(s2);
#pragma unroll
    for (int q = 0; q < 4; q++) {
      float dx1 = rstd * (dxh[q] - s1 * (1.f / HID) - xhL[l + 64 * q] * (s2 * (1.f / HID)));
      dx1L[l + 64 * q] = dx1;
    }
    const float* row1 = h1W + (size_t)l * HID;
    for (int j4 = 0; j4 < HID / 4; j4++) {
      float4 w4 = *(const float4*)(row1 + j4 * 4);
      float4 d4 = *(const float4*)&dx1L[j4 * 4];
      g += w4.x * d4.x + w4.y * d4.y + w4.z * d4.z + w4.w * d4.w;
    }
  }
  float r2n = softt(r2v - 0.1f * g, 0.001f);
  int fl = 0;
  if (__ballot(r2n != r2v) != 0ull) fl |= 1;
  if (__ballot(r2n != 0.f) == 0ull) fl |= 2;
  return make_float2(r2n, __int_as_float(fl));
}

// ---------------- prep: G (folded), U, SX, flag, zero loss slots --------------
__global__ __launch_bounds__(256) void k_prep(const float* __restrict__ X,
                                              const float* __restrict__ decb,
                                              const float* __restrict__ decW,
                                              const float* __restrict__ h1W,
                                              const float* __restrict__ h1b,
                                              const float* __restrict__ lns,
                                              const float* __restrict__ lnb,
                                              const float* __restrict__ h2W,
                                              const float* __restrict__ h2b,
                                              const float* __restrict__ h3W,
                                              const float* __restrict__ h3b,
                                              float* __restrict__ ws,
                                              float* __restrict__ out) {
  __shared__ __align__(16) float As[8][IN_DIM];    // 16 KB
  __shared__ float scr[256];
  __shared__ __align__(16) float aF[HID], xhF[HID], x2F[HID];
  __shared__ __align__(16) float wF[MIX];
  __shared__ float rsF[1];
  float* G = ws + OFF_G;
  float* U = ws + OFF_U;
  float* SX = ws + OFF_SX;
  const int tid = threadIdx.x;
  const int bx = blockIdx.x;

  if (bx == 528) {  // absorbing-state probe, wave 0 only
    if (tid < 64) {
      int z = hyp_fwd_cold(tid, 0.f, 1, h1W, h1b, lns, lnb, h2W, h2b, h3W, h3b,
                           aF, xhF, x2F, wF, rsF);
      if (tid == 0) ((int*)(ws + OFF_FLAG))[0] = z;
    }
    return;
  }
  const bool isG = (bx >= 512);

  if (bx == 0 && tid < 3) out[tid] = 0.f;             // loss accumulators (serial)
  if (bx == 0 && tid < 48) ws[OFF_LOSS + tid] = 0.f;  // loss slots (fast)

  // ---- stage A rows (X - b, or decW rows for G blocks) + SX partials ----
  {
    int g = tid >> 5;             // row 0..7
    int f0 = tid & 31;            // float4 slot base
    if (!isG) {
      int row0 = bx * 8;
      float p = 0.f;
#pragma unroll
      for (int q = 0; q < 4; q++) {
        int f4 = f0 + 32 * q;
        float4 xv = *reinterpret_cast<const float4*>(X + (size_t)(row0 + g) * IN_DIM + f4 * 4);
        float4 bv = *reinterpret_cast<const float4*>(decb + f4 * 4);
        float4 v = make_float4(xv.x - bv.x, xv.y - bv.y, xv.z - bv.z, xv.w - bv.w);
        *reinterpret_cast<float4*>(&As[g][f4 * 4]) = v;
        p += v.x * v.x + v.y * v.y + v.z * v.z + v.w * v.w;
      }
      scr[tid] = p;
    } else {
      int row0 = (bx - 512) * 8;
#pragma unroll
      for (int q = 0; q < 4; q++) {
        int f4 = f0 + 32 * q;
        float4 v = *reinterpret_cast<const float4*>(decW + (size_t)(row0 + g) * IN_DIM + f4 * 4);
        *reinterpret_cast<float4*>(&As[g][f4 * 4]) = v;
      }
    }
  }
  __syncthreads();
  if (!isG && tid < 8) {
    float s = 0.f;
#pragma unroll
    for (int q = 0; q < 32; q++) s += scr[tid * 32 + q];
    SX[bx * 8 + tid] = s;
  }

  const int j = tid & 127;        // output column
  const int gh = tid >> 7;        // row-half (4 rows each)
  float acc[4] = {0.f, 0.f, 0.f, 0.f};
  const float* wrow = decW + (size_t)j * IN_DIM;

#pragma unroll 4
  for (int k4 = 0; k4 < IN_DIM / 4; k4++) {
    float4 w4 = *reinterpret_cast<const float4*>(wrow + k4 * 4);
#pragma unroll
    for (int gi = 0; gi < 4; gi++) {
      // gg uniform per wave -> As reads are broadcasts
      float4 a4 = *reinterpret_cast<const float4*>(&As[gh * 4 + gi][k4 * 4]);
      acc[gi] += w4.x * a4.x + w4.y * a4.y + w4.z * a4.z + w4.w * a4.w;
    }
  }

  if (!isG) {
    int row0 = bx * 8;
#pragma unroll
    for (int gi = 0; gi < 4; gi++)
      U[(size_t)(row0 + gh * 4 + gi) * R_DIM + j] = acc[gi];
  } else {
    int row0 = (bx - 512) * 8;
#pragma unroll
    for (int gi = 0; gi < 4; gi++) {
      int rr = row0 + gh * 4 + gi;
      float gv = -0.2f * acc[gi];            // fold M = 0.8I - 0.2G
      if (rr == j) gv += 0.8f;
      G[(size_t)rr * R_DIM + j] = gv;
    }
  }
}

// ---------------- FAST path: one block per (b,t); absorbing state only -------
// Bit-exact R5 body: the session's proven 90us optimum. No pins (R9: pins turn
// benign L2-remat into scratch spill), no fused finalization (R12 isolated it:
// the required __threadfence is a per-block device-scope L2 writeback, ~50us
// across 4096 blocks -- a separate 2us k_fin launch is 25x cheaper).
__global__ __launch_bounds__(256, 4) void k_ista(float* __restrict__ ws,
                                                 float* __restrict__ out) {
  if (((const int*)(ws + OFF_FLAG))[0] == 0) return;  // cold mode: serial path
  __shared__ __align__(16) float rbuf[2][R_DIM];
  __shared__ float scr[8];

  const int tid = threadIdx.x;
  const int w = tid >> 6;
  const int l6 = tid & 63;
  const int i = (w << 5) + (l6 & 31);
  const int kh = l6 >> 5;
  const int bt = blockIdx.x;
  const int b = bt >> 4;
  const int t = bt & 15;
  const float* Gg = ws + OFF_G;
  const float* Ug = ws + OFF_U;

  float Ga[64];
#pragma unroll
  for (int kk = 0; kk < 64; kk++)
    Ga[kk] = Gg[(size_t)(kh * 64 + kk) * R_DIM + i];

  const float u = Ug[(size_t)bt * R_DIM + i];
  const float u02 = 0.2f * u;

  auto mvhalf = [&](const float* vptr) {
    const float* vp = vptr + (kh << 6);
    float p0 = 0.f, p1 = 0.f, p2 = 0.f, p3 = 0.f;
#pragma unroll
    for (int k4 = 0; k4 < 16; k4++) {
      float4 v4 = *reinterpret_cast<const float4*>(vp + k4 * 4);
      p0 += v4.x * Ga[k4 * 4 + 0];
      p1 += v4.y * Ga[k4 * 4 + 1];
      p2 += v4.z * Ga[k4 * 4 + 2];
      p3 += v4.w * Ga[k4 * 4 + 3];
    }
    float pm = (p0 + p1) + (p2 + p3);
    return pairsum32(pm);
  };

  // it = 0: r_prev = warm = 0 -> r = softt(0.2*u)
  float r = softt(u02, 0.001f);
  if (kh == 0) rbuf[1][i] = r;
  __syncthreads();
#pragma unroll 1
  for (int it = 1; it < MAX_IT; it++) {
    float mv = mvhalf(rbuf[it & 1]);
    r = softt(mv + u02, 0.001f);
    if (kh == 0) rbuf[(it & 1) ^ 1][i] = r;   // write buffer != read buffer
    __syncthreads();
  }
  // last write (it=11) went to rbuf[0]; barrier done.
  float mvf = mvhalf(rbuf[0]);
  float gb = 0.8f * r - mvf;                   // = 0.2*(G r)_i
  float l1 = (kh == 0) ? (r * (5.f * gb) - 2.f * r * u) : 0.f;
  float l2 = (kh == 0) ? (r * r) : 0.f;
  l1 = wsum(l1); l2 = wsum(l2);
  if (l6 == 0) { scr[w * 2 + 0] = l1; scr[w * 2 + 1] = l2; }
  __syncthreads();
  if (tid == 0) {
    float s1 = scr[0] + scr[2] + scr[4] + scr[6];
    float s2 = scr[1] + scr[3] + scr[5] + scr[7];
    float sx = ws[OFF_SX + bt];
    float* loss = ws + OFF_LOSS;
    atomicAdd(&loss[0 * 16 + t], sx);          // spat_rhat: decode(0) vs x
    atomicAdd(&loss[1 * 16 + t], s1 + sx);     // spat_rbar
    atomicAdd(&loss[2 * 16 + t], s2);          // temp loss: ||r - 0||^2
  }
  if (t == T_SZ - 1 && kh == 0) out[3 + b * R_DIM + i] = r;
  if (t == 0 && w == 0) out[3 + B_SZ * R_DIM + b * R2_DIM + l6] = 0.f;
}

__global__ void k_fin(const float* __restrict__ ws, float* __restrict__ out) {
  if (((const int*)(ws + OFF_FLAG))[0] == 0) return;
  int k = threadIdx.x;
  if (k < 3) {
    float s = 0.f;
#pragma unroll
    for (int t = 0; t < 16; t++) s += ws[OFF_LOSS + k * 16 + t];
    out[k] = s * (1.f / (B_SZ * T_SZ));
  }
}

// ---------------- SERIAL fallback: bit-faithful R0 body (proven green) -------
__global__ __launch_bounds__(256, 1) void k_main(
    float* __restrict__ ws, const float* __restrict__ T2,
    const float* __restrict__ h1W, const float* __restrict__ h1b,
    const float* __restrict__ lns, const float* __restrict__ lnb,
    const float* __restrict__ h2W, const float* __restrict__ h2b,
    const float* __restrict__ h3W, const float* __restrict__ h3b,
    float* __restrict__ out) {
  if (((const int*)(ws + OFF_FLAG))[0] != 0) return;  // fast path covers
  __shared__ __align__(16) float rbuf[2][R_DIM];
  __shared__ __align__(16) float rhL[R_DIM];
  __shared__ __align__(16) float cS[MIX * 129];
  __shared__ __align__(16) float aL[HID];
  __shared__ __align__(16) float xhL[HID];
  __shared__ __align__(16) float x2L[HID];
  __shared__ __align__(16) float dx1L[HID];
  __shared__ __align__(16) float dx2L[HID];
  __shared__ __align__(16) float wL[MIX];
  __shared__ __align__(16) float dx3L[MIX];
  __shared__ __align__(16) float eL[R_DIM];
  __shared__ __align__(16) float rpL[R_DIM];
  __shared__ float rstdL[1];
  __shared__ int cstL[1];
  __shared__ int flagL[1];

  const int tid = threadIdx.x;
  const int w = tid >> 6;
  const int l6 = tid & 63;
  const int i = (w << 5) + (l6 & 31);
  const int kh = l6 >> 5;
  const int b = blockIdx.x;
  const float* Gg = ws + OFF_G;
  const float* Ug = ws + OFF_U;
  const float* SXg = ws + OFF_SX;

  float r2v = 0.f;
  bool zr2 = true, rhv;

  if (w == 0) {
    int z = hyp_fwd_cold(l6, 0.f, 1, h1W, h1b, lns, lnb, h2W, h2b, h3W, h3b,
                         aL, xhL, x2L, wL, rstdL);
    if (l6 == 0) flagL[0] = z;
  }
  __syncthreads();
  bool zw = flagL[0] != 0;

  float Ga[64];
#pragma unroll
  for (int kk = 0; kk < 64; kk++)
    Ga[kk] = Gg[(size_t)(kh * 64 + kk) * R_DIM + i];

  float rOwn = 0.f;
  float lc0 = 0.f, lc1 = 0.f, lc2 = 0.f, sxa = 0.f;

  auto mvhalf = [&](const float* vptr) {
    const float* vp = vptr + (kh << 6);
    float p0 = 0.f, p1 = 0.f, p2 = 0.f, p3 = 0.f;
#pragma unroll
    for (int k4 = 0; k4 < 16; k4++) {
      float4 v4 = *reinterpret_cast<const float4*>(vp + k4 * 4);
      p0 += v4.x * Ga[k4 * 4 + 0];
      p1 += v4.y * Ga[k4 * 4 + 1];
      p2 += v4.z * Ga[k4 * 4 + 2];
      p3 += v4.w * Ga[k4 * 4 + 3];
    }
    float pm = (p0 + p1) + (p2 + p3);
    return pm + __shfl_xor(pm, 32, 64);
  };

  float rh_own = 0.f;
  auto refresh_rh = [&]() {
    if (zw) { rh_own = 0.f; return; }
    __syncthreads();
    if (w == 0) {
      float2 rr = rhat_cold(l6, T2, cS, cstL, rpL, wL);
      rhL[l6] = rr.x; rhL[64 + l6] = rr.y;
    }
    __syncthreads();
    rh_own = rhL[i];
  };

  float un = Ug[(size_t)(b * T_SZ) * R_DIM + i];
  float sxn = SXg[b * T_SZ];

#pragma unroll 1
  for (int t = 0; t < T_SZ; t++) {
    float u = un, sxv = sxn;
    if (t < T_SZ - 1) {
      un = Ug[(size_t)(b * T_SZ + t + 1) * R_DIM + i];
      sxn = SXg[b * T_SZ + t + 1];
    }
    float u02 = 0.2f * u;
    if (kh == 0) rpL[i] = rOwn;
    if (tid == 0) cstL[0] = 0;
    refresh_rh();
    rhv = true;
    rOwn = rh_own;
    __syncthreads();
    if (kh == 0) rbuf[0][i] = rOwn;
    __syncthreads();
    bool rzero = zw;
#pragma unroll 1
    for (int it = 0; it < MAX_IT; it++) {
      if (!rhv) { refresh_rh(); rhv = true; }
      float mv = 0.f;
      if (!rzero) mv = mvhalf(rbuf[it & 1]);
      rzero = false;
      float rNew = softt(mv + 0.2f * rh_own + u02, 0.001f);
      if (kh == 0) {
        eL[i] = rOwn - rh_own;
        rbuf[(it & 1) ^ 1][i] = rNew;
      }
      rOwn = rNew;
      __syncthreads();
      if (!(zw && zr2)) {
        if (w == 0) {
          float2 br = hyp_bwd_cold(l6, r2v, zw ? 1 : 0, T2, h1W, lns, h2W, h3W,
                                   cS, cstL, rpL, eL, aL, xhL, wL,
                                   dx3L, dx2L, dx1L, rstdL);
          r2v = br.x;
          if (l6 == 0) flagL[0] = __float_as_int(br.y);
        }
        __syncthreads();
        int fl = flagL[0];
        zr2 = (fl & 2) != 0;
        if (fl & 1) {
          if (w == 0) {
            int z = hyp_fwd_cold(l6, r2v, zr2 ? 1 : 0, h1W, h1b, lns, lnb,
                                 h2W, h2b, h3W, h3b, aL, xhL, x2L, wL, rstdL);
            if (l6 == 0) flagL[0] = z;
          }
          __syncthreads();
          zw = flagL[0] != 0;
          rhv = false;
        }
      }
    }
    if (!rhv) { refresh_rh(); rhv = true; }
    {
      float mv = mvhalf(rbuf[MAX_IT & 1]);
      float gb = 0.8f * rOwn - mv;
      if (kh == 0) lc1 += rOwn * (5.f * gb) - 2.f * rOwn * u;
      if (zw) {
        if (kh == 0) lc2 += rOwn * rOwn;
      } else {
        float mvh = mvhalf(rhL);
        float gh = 0.8f * rh_own - mvh;
        if (kh == 0) {
          lc0 += rh_own * (5.f * gh) - 2.f * rh_own * u;
          float d = rOwn - rh_own;
          lc2 += d * d;
        }
      }
      if (tid == 0) sxa += sxv;
    }
  }

  const float inv = 1.f / (B_SZ * T_SZ);
  float t0 = wsum(lc0), t1 = wsum(lc1), t2 = wsum(lc2);
  if (l6 == 0) {
    float s = (w == 0) ? sxa : 0.f;
    atomicAdd(&out[0], (t0 + s) * inv);
    atomicAdd(&out[1], (t1 + s) * inv);
    atomicAdd(&out[2], t2 * inv);
  }
  if (kh == 0) out[3 + b * R_DIM + i] = rOwn;
  if (w == 0) out[3 + B_SZ * R_DIM + b * R2_DIM + l6] = r2v;
}

extern "C" void kernel_launch(void* const* d_in, const int* in_sizes, int n_in,
                              void* d_out, int out_size, void* d_ws, size_t ws_size,
                              hipStream_t stream) {
  const float* X = (const float*)d_in[0];
  const float* decW = (const float*)d_in[1];
  const float* decb = (const float*)d_in[2];
  const float* temporal = (const float*)d_in[3];
  const float* h1W = (const float*)d_in[4];
  const float* h1b = (const float*)d_in[5];
  const float* lns = (const float*)d_in[6];
  const float* lnb = (const float*)d_in[7];
  const float* h2W = (const float*)d_in[8];
  const float* h2b = (const float*)d_in[9];
  const float* h3W = (const float*)d_in[10];
  const float* h3b = (const float*)d_in[11];
  float* ws = (float*)d_ws;  // ~2.22 MiB used
  float* out = (float*)d_out;

  k_prep<<<529, 256, 0, stream>>>(X, decb, decW, h1W, h1b, lns, lnb,
                                  h2W, h2b, h3W, h3b, ws, out);
  k_main<<<B_SZ, 256, 0, stream>>>(ws, temporal, h1W, h1b, lns, lnb,
                                   h2W, h2b, h3W, h3b, out);
  k_ista<<<B_SZ * T_SZ, 256, 0, stream>>>(ws, out);
  k_fin<<<1, 64, 0, stream>>>(ws, out);
}